// Round 24
// baseline (930.578 us; speedup 1.0000x reference)
//
#include <hip/hip_runtime.h>
#include <stdint.h>

// Fixed problem config
#define NN   2
#define ANU  5
#define CH   64
#define HH   96
#define WW   96
#define KK   6
#define PSHh 8
#define PNHh 12
#define BB   (NN*PNHh)        // 24
#define PP   (ANU*WW)         // 480
#define CCD  (CH*ANU*PSHh)    // 2560
#define IMG_HW (HH*WW)            // 9216
#define IMG_STRIDE (CH*HH*WW)     // 589824 floats per input image
#define LFV_IMG (CH*ANU*HH)       // 30720 elems per (n,v,w) image in lfVh / a1h

typedef int   i32x4 __attribute__((ext_vector_type(4)));
typedef float f32x4 __attribute__((ext_vector_type(4)));

__device__ __forceinline__ unsigned short f2bf(float f) {
    unsigned int u = __float_as_uint(f);
    return (unsigned short)((u + 0x7FFFu + ((u >> 16) & 1u)) >> 16);
}

__device__ __forceinline__ void mfma_bf16_16x16x32(f32x4& d, i32x4 a, i32x4 b) {
    asm volatile("v_mfma_f32_16x16x32_bf16 %0, %1, %2, %0"
                 : "+v"(d) : "v"(a), "v"(b));
}

// ---------------------------------------------------------------------------
// K0: transpose lf_fea[(n,u,v)][c][h][w] -> lfVh[(n,v,w)][c][u][h] (bf16)
//     (r23 verbatim, passing)
// ---------------------------------------------------------------------------
__global__ __launch_bounds__(256) void k0_lfv(const float* __restrict__ lf_fea,
                                              unsigned short* __restrict__ lfVh) {
    int bc  = blockIdx.x;          // img*64 + c
    int img = bc >> 6;
    int c   = bc & 63;
    int n = img / 25, r = img % 25, u = r / 5, v = r % 5;
    const float* src = lf_fea + (size_t)bc * IMG_HW;
    __shared__ float tile[96][97];
    for (int e = threadIdx.x; e < 96*96; e += 256) {
        int h = e / 96, w = e % 96;
        tile[h][w] = src[e];
    }
    __syncthreads();
    size_t base = (size_t)((n*5 + v)*96) * LFV_IMG + (size_t)c*480 + u*96;
    for (int e = threadIdx.x; e < 96*96; e += 256) {
        int w = e / 96, h = e % 96;
        lfVh[base + (size_t)w * LFV_IMG + h] = f2bf(tile[h][w]);
    }
}

// ---------------------------------------------------------------------------
// K0g: pack lf_fea -> lfG[(n,pnh)][p=(v,w)][c][u][psh] (bf16, gather-optimal)
//      (r23 verbatim, passing)
// ---------------------------------------------------------------------------
__global__ __launch_bounds__(256) void k0g_pack(const float* __restrict__ lf,
                                                unsigned short* __restrict__ lfG) {
    int blk = blockIdx.x;            // ((img*12 + pnh)*4 + ct), grid 2400
    int ct = blk & 3; int r = blk >> 2;
    int pnh = r % 12, img = r / 12;
    int n = img / 25, rr = img % 25, u = rr / 5, v = rr % 5;
    int c0 = ct * 16;
    __shared__ float tile[16][8][97];
    int t = threadIdx.x;
    const float* src = lf + (size_t)img * IMG_STRIDE + (size_t)c0 * IMG_HW + pnh*768;
#pragma unroll
    for (int i = 0; i < 12; ++i) {
        int e = i*256 + t;           // 3072 float4
        int ci = e / 192, r2 = e % 192, psh = r2 / 24, q2 = r2 % 24;
        float4 vv = *(const float4*)(src + (size_t)ci*IMG_HW + psh*96 + q2*4);
        tile[ci][psh][q2*4+0]=vv.x; tile[ci][psh][q2*4+1]=vv.y;
        tile[ci][psh][q2*4+2]=vv.z; tile[ci][psh][q2*4+3]=vv.w;
    }
    __syncthreads();
    size_t ob = ((size_t)((n*12+pnh)*480 + v*96)) * 2560 + c0*40 + u*8;
#pragma unroll
    for (int i = 0; i < 24; ++i) {
        int e = i*256 + t;           // 6144 units = (w, ci, psh-pair)
        int w = e >> 6, r2 = e & 63, ci = r2 >> 2, pp = r2 & 3;
        size_t off = ob + (size_t)w*2560 + ci*40 + pp*2;
        lfG[off]     = f2bf(tile[ci][pp*2][w]);
        lfG[off + 1] = f2bf(tile[ci][pp*2+1][w]);
    }
}

// ---------------------------------------------------------------------------
// K1: sq[b][p] (fp64 accumulate), 8-way column split per row; 360 blocks
// ---------------------------------------------------------------------------
__global__ __launch_bounds__(256) void k1_sq(const float* __restrict__ lf_fea,
                                             float* __restrict__ sq) {
    int t = threadIdx.x;
    int row = blockIdx.x * 32 + (t & 31);      // 0..11519
    int cp = t >> 5;                           // 0..7
    int b = row / PP, p = row % PP;
    int n = b / PNHh, pnh = b % PNHh;
    int v = p / WW, w = p % WW;
    double acc = 0.0;
    for (int ci = 0; ci < 8; ++ci) {
        int c = cp * 8 + ci;
        for (int u = 0; u < 5; ++u) {
            const float* s = lf_fea + ((size_t)((n*25 + u*5 + v)*64 + c)) * IMG_HW
                           + pnh*8*96 + w;
#pragma unroll
            for (int psh = 0; psh < 8; ++psh) {
                float x = s[psh*96];
                acc += (double)x * (double)x;
            }
        }
    }
    __shared__ double red[256];
    red[t] = acc;
    __syncthreads();
    if (t < 32) {
        double ss = 0.0;
#pragma unroll
        for (int j = 0; j < 8; ++j) ss += red[j * 32 + t];
        sq[blockIdx.x * 32 + t] = (float)ss;
    }
}

// ---------------------------------------------------------------------------
// K2a: partial Gram, symmetric (vr<=vc), K-split 4; grid 1440.
//      vs r23: (1) staging col rotation w = sw + 8*((j+sr)%12) -> write banks
//      spread 32-wide (2-way, free); (2) register prefetch double-buffer:
//      chunk k+1 global loads issue right after the post-write barrier and
//      complete under chunk k's compute. LDS contents per chunk and the
//      compute/summation order are BIT-IDENTICAL to r23 -> zero top-k risk.
// ---------------------------------------------------------------------------
__global__ __launch_bounds__(256) void k2a_gram(const float* __restrict__ lf_fea,
                                                float* __restrict__ Gpart) {
    const int VRt[15] = {0,0,0,0,0,1,1,1,1,2,2,2,3,3,4};
    const int VCt[15] = {0,1,2,3,4,1,2,3,4,2,3,4,3,4,4};
    int blk = blockIdx.x;            // b*60 + pr*4 + ks
    int b  = blk / 60;
    int r0 = blk % 60;
    int pr = r0 / 4, ks = r0 % 4;
    int vr = VRt[pr], vc = VCt[pr];
    int n = b / PNHh, pnh = b % PNHh;

    __shared__ float As[32][96];
    __shared__ float Bs[32][96];

    int t  = threadIdx.x;
    int tx = t & 31, ty = t >> 5;    // 32 x 8 compute tiling
    int sr = t >> 3, sw = t & 7;     // staging: row 0..31, col-base 0..7
    float acc[12][3] = {};
    float ra[12], rb[12];

    int kbase = ks * 640;
    // prefetch chunk 0
    {
        int cc = kbase + sr;
        int c = cc / 40, r2 = cc % 40, u = r2 >> 3, psh = r2 & 7;
        size_t off = ((size_t)((n*25 + u*5)*64 + c)) * IMG_HW + (pnh*8 + psh)*96;
        const float* pa = lf_fea + off + (size_t)vr * IMG_STRIDE;
        const float* pb = lf_fea + off + (size_t)vc * IMG_STRIDE;
#pragma unroll
        for (int j = 0; j < 12; ++j) {
            int w = sw + 8 * ((j + sr) % 12);
            ra[j] = pa[w];
            rb[j] = pb[w];
        }
    }

    for (int ch = 0; ch < 20; ++ch) {
        // write current chunk to LDS (2-way banks: sw x ((j+sr)&3) spread)
#pragma unroll
        for (int j = 0; j < 12; ++j) {
            int w = sw + 8 * ((j + sr) % 12);
            As[sr][w] = ra[j];
            Bs[sr][w] = rb[j];
        }
        __syncthreads();
        // prefetch next chunk (latency hides under compute below)
        if (ch < 19) {
            int cc = kbase + (ch + 1) * 32 + sr;
            int c = cc / 40, r2 = cc % 40, u = r2 >> 3, psh = r2 & 7;
            size_t off = ((size_t)((n*25 + u*5)*64 + c)) * IMG_HW + (pnh*8 + psh)*96;
            const float* pa = lf_fea + off + (size_t)vr * IMG_STRIDE;
            const float* pb = lf_fea + off + (size_t)vc * IMG_STRIDE;
#pragma unroll
            for (int j = 0; j < 12; ++j) {
                int w = sw + 8 * ((j + sr) % 12);
                ra[j] = pa[w];
                rb[j] = pb[w];
            }
        }
        // compute (identical to r23)
        float accC[12][3] = {};
#pragma unroll
        for (int kc = 0; kc < 32; ++kc) {
            float a[12], bq[3];
            *(float4*)&a[0] = *(const float4*)&As[kc][ty*12 + 0];
            *(float4*)&a[4] = *(const float4*)&As[kc][ty*12 + 4];
            *(float4*)&a[8] = *(const float4*)&As[kc][ty*12 + 8];
#pragma unroll
            for (int j = 0; j < 3; ++j) bq[j] = Bs[kc][tx*3 + j];
#pragma unroll
            for (int i = 0; i < 12; ++i)
#pragma unroll
                for (int j = 0; j < 3; ++j)
                    accC[i][j] = fmaf(a[i], bq[j], accC[i][j]);
        }
#pragma unroll
        for (int i = 0; i < 12; ++i)
#pragma unroll
            for (int j = 0; j < 3; ++j)
                acc[i][j] += accC[i][j];
        __syncthreads();
    }

    size_t gbase = ((size_t)(ks*600 + b*25 + vr*5 + vc)) * 9216;
#pragma unroll
    for (int i = 0; i < 12; ++i)
#pragma unroll
        for (int j = 0; j < 3; ++j)
            Gpart[gbase + (ty*12 + i)*96 + tx*3 + j] = acc[i][j];

    if (vr != vc) {
        size_t gbt = ((size_t)(ks*600 + b*25 + vc*5 + vr)) * 9216;
#pragma unroll
        for (int i = 0; i < 12; ++i)
#pragma unroll
            for (int j = 0; j < 3; ++j)
                Gpart[gbt + (tx*3 + j)*96 + ty*12 + i] = acc[i][j];
    }
}

// ---------------------------------------------------------------------------
// K2b: dist[b][p][q] = sq_p + sq_q - 2 * sum_ks Gpart   (r23 verbatim)
// ---------------------------------------------------------------------------
__global__ __launch_bounds__(256) void k2b_dist(const float* __restrict__ Gpart,
                                                const float* __restrict__ sq,
                                                float* __restrict__ dist) {
    int tid = blockIdx.x * 256 + threadIdx.x;   // grid 5400: exactly 1,382,400
    int b = tid / 57600;
    int r = tid % 57600;
    int p = r / 120, qt = r % 120;
    int vr = p / 96, pl = p % 96;
    int vc = qt / 24;
    int ql4 = (qt % 24) * 4;

    size_t tb = ((size_t)(b*25 + vr*5 + vc)) * 9216 + pl*96 + ql4;
    float4 g0 = *(const float4*)(Gpart + tb);
    float4 g1 = *(const float4*)(Gpart + tb +  600ull*9216);
    float4 g2 = *(const float4*)(Gpart + tb + 1200ull*9216);
    float4 g3 = *(const float4*)(Gpart + tb + 1800ull*9216);
    float gx = g0.x + g1.x + g2.x + g3.x;
    float gy = g0.y + g1.y + g2.y + g3.y;
    float gz = g0.z + g1.z + g2.z + g3.z;
    float gw = g0.w + g1.w + g2.w + g3.w;

    float  sqp = sq[b*480 + p];
    float4 sqq = *(const float4*)(sq + b*480 + vc*96 + ql4);
    float4 d;
    d.x = sqp + sqq.x - 2.0f * gx;
    d.y = sqp + sqq.y - 2.0f * gy;
    d.z = sqp + sqq.z - 2.0f * gz;
    d.w = sqp + sqq.w - 2.0f * gw;
    *(float4*)(dist + (size_t)b*230400 + (size_t)p*480 + vc*96 + ql4) = d;
}

// ---------------------------------------------------------------------------
// K3: per-row top-6  (passing, verbatim)
// ---------------------------------------------------------------------------
__global__ __launch_bounds__(256) void k3_topk(const float* __restrict__ dist,
                                               int* __restrict__ idx) {
    int wid  = (blockIdx.x * 256 + threadIdx.x) >> 6;  // global wave id
    int lane = threadIdx.x & 63;
    int b = wid / PP, p = wid % PP;
    const float* row = dist + (size_t)b * PP * PP + (size_t)p * PP;

    unsigned long long key[8];
#pragma unroll
    for (int j = 0; j < 8; ++j) {
        int q = j*64 + lane;
        if (q < PP) {
            unsigned int f = __float_as_uint(row[q]);
            unsigned int mono = f ^ ((f & 0x80000000u) ? 0xFFFFFFFFu : 0x80000000u);
            key[j] = ((unsigned long long)mono << 32) | (unsigned int)q;
        } else {
            key[j] = ~0ull;
        }
    }
    int* outp = idx + ((size_t)b*PP + p) * KK;
    for (int k = 0; k < KK; ++k) {
        unsigned long long m = key[0];
#pragma unroll
        for (int j = 1; j < 8; ++j) m = (key[j] < m) ? key[j] : m;
        for (int s = 1; s < 64; s <<= 1) {
            unsigned long long o = __shfl_xor(m, s, 64);
            m = (o < m) ? o : m;
        }
        if (lane == 0) outp[k] = (int)(m & 0xFFFFFFFFu);
#pragma unroll
        for (int j = 0; j < 8; ++j) if (key[j] == m) key[j] = ~0ull;
    }
}

// ---------------------------------------------------------------------------
// kw1: w1 -> bf16 flat copy w1h[co][k*64+c]  (passing, verbatim)
// ---------------------------------------------------------------------------
__global__ __launch_bounds__(256) void kw1_conv(const float* __restrict__ w1,
                                                unsigned short* __restrict__ w1h) {
    int e = blockIdx.x * 256 + threadIdx.x;   // 24576 total, grid 96
    if (e < 24576) w1h[e] = f2bf(w1[e]);
}

// ---------------------------------------------------------------------------
// kw2: reorder w2 -> bf16 w2h[co][cc][tap][ci64] (passing, verbatim)
// ---------------------------------------------------------------------------
__global__ __launch_bounds__(256) void kw2_conv(const float* __restrict__ w2,
                                                unsigned short* __restrict__ w2h) {
    int e = blockIdx.x * 256 + threadIdx.x;   // 73728 total
    if (e < 73728) {
        int co = e / 1152, r = e % 1152;
        int cc = r / 576, r2 = r % 576;
        int tap = r2 / 64, ci_l = r2 % 64;
        w2h[e] = f2bf(w2[co*1152 + (cc*64 + ci_l)*9 + tap]);
    }
}

// ---------------------------------------------------------------------------
// K4: gather + 1x1 conv via inline-asm MFMA  (r23 verbatim, passing)
// ---------------------------------------------------------------------------
__global__ __launch_bounds__(256) void k4_conv1(const unsigned short* __restrict__ lfG,
                                                const unsigned short* __restrict__ w1h,
                                                const int* __restrict__ idxg,
                                                unsigned short* __restrict__ a1h) {
    int blk = blockIdx.x;            // b*240 + ptile
    int b = blk / 240, ptile = blk % 240;
    int n = b / PNHh, pnh = b % PNHh;
    int p0 = ptile * 2;

    __shared__ unsigned short Bs[80][384];   // [col][swizzled krow] bf16
    __shared__ int idxs[12];

    int t = threadIdx.x;
    if (t < 12) idxs[t] = idxg[(b*PP + p0 + t/6)*KK + (t % 6)];
    __syncthreads();

    // stage: 3840 units of 16B; unit = (pl, k, m); m -> (c = m/5, u = m%5)
    for (int i = 0; i < 15; ++i) {
        int e = i * 256 + t;         // 3840 exactly
        int pl = e / 1920, r = e % 1920;
        int k = r / 320, m = r % 320;
        int c = m / 5, u = m % 5;
        int q = idxs[pl*6 + k];
        i32x4 vv = *(const i32x4*)(lfG + ((size_t)(b*480 + q))*2560 + m*8);
        int colbase = pl*40 + u*8;   // multiple of 8
        int krow = k*64 + c;
        int kc = krow >> 3, kl = krow & 7;
        int kbase = kc & ~7, klo = kc & 7;
#pragma unroll
        for (int j = 0; j < 4; ++j) {
            unsigned int d = (unsigned int)vv[j];
            int j0 = 2*j, j1 = 2*j + 1;
            Bs[colbase + j0][((kbase | (klo ^ j0)) << 3) | kl] =
                (unsigned short)(d & 0xFFFFu);
            Bs[colbase + j1][((kbase | (klo ^ j1)) << 3) | kl] =
                (unsigned short)(d >> 16);
        }
    }
    __syncthreads();

    int lane = t & 63, wv = t >> 6;
    int l15 = lane & 15, hi = lane >> 4;
    int co0 = wv * 16;
    f32x4 acc[5] = {};
#pragma unroll
    for (int f = 0; f < 5; ++f)
        asm volatile("s_nop 1" : "+v"(acc[f]));

    const unsigned short* ap = w1h + (size_t)(co0 + l15) * 384 + hi * 8;
    for (int ks = 0; ks < 12; ++ks) {
        i32x4 a = *(const i32x4*)(ap + ks * 32);
        asm volatile("s_nop 1" : "+v"(a));
#pragma unroll
        for (int f = 0; f < 5; ++f) {
            int col = f * 16 + l15;
            int ch = ks * 4 + hi;            // chunk 0..47
            int chs = (ch & ~7) | ((ch & 7) ^ (col & 7));
            i32x4 bv = *(const i32x4*)&Bs[col][chs << 3];
            mfma_bf16_16x16x32(acc[f], a, bv);
        }
    }
#pragma unroll
    for (int f = 0; f < 5; ++f)
        asm volatile("s_nop 7\ns_nop 7" : "+v"(acc[f]));

    // epilogue: leaky + bf16 u16 stores; D map: col=lane&15, row=hi*4+reg
#pragma unroll
    for (int f = 0; f < 5; ++f) {
        int col = f * 16 + l15;
        int pg = p0 + col / 40, rr = col % 40;
        int u = rr >> 3, psh = rr & 7;
        size_t base = (size_t)((n*5 + pg/96)*96 + (pg%96)) * LFV_IMG
                    + (size_t)u * 96 + pnh*8 + psh;
#pragma unroll
        for (int rg = 0; rg < 4; ++rg) {
            float x = acc[f][rg];
            x = x > 0.f ? x : 0.1f * x;
            a1h[base + (size_t)(co0 + hi*4 + rg) * 480] = f2bf(x);
        }
    }
}

// ---------------------------------------------------------------------------
// K5n: 3x3 conv via inline-asm MFMA, u-fused tile  (r23 verbatim, passing)
// ---------------------------------------------------------------------------
__global__ __launch_bounds__(256) void k5n_conv3(const unsigned short* __restrict__ lfVh,
                                                 const unsigned short* __restrict__ a1h,
                                                 const unsigned short* __restrict__ w2h,
                                                 float* __restrict__ outp) {
    int blk = blockIdx.x;             // grid 1440 = nv*144 + wt*6 + ht
    int ht = blk % 6;  int r = blk / 6;
    int wt = r % 24;   int nv = r / 24;    // nv = n*5 + v
    int w0 = wt * 4, h0 = ht * 16;
    int imgbase = nv * 96 + w0;

    __shared__ unsigned short ins[360][64];   // 46,080 B

    int t = threadIdx.x;
    int lane = t & 63, wv = t >> 6, l15 = lane & 15, hi = lane >> 4;
    int wl = l15 & 3;                 // output w within tile
    int hl = wv * 4 + (l15 >> 2);     // output h within tile (wave-split)

    f32x4 acc[5][4] = {};
#pragma unroll
    for (int u = 0; u < 5; ++u)
#pragma unroll
        for (int j = 0; j < 4; ++j)
            asm volatile("s_nop 1" : "+v"(acc[u][j]));

    for (int cc = 0; cc < 2; ++cc) {
        const unsigned short* basep = cc ? a1h : lfVh;
        if (cc) __syncthreads();
        // stage: e = (ci, uin, w, g): 4 h-values, b16 scatter with guards
        for (int i = 0; i < 30; ++i) {
            int e = i * 256 + t;              // 7680 = 64*5*4*6
            int g   = e % 6;
            int w   = (e / 6) & 3;
            int uin = (e / 24) % 5;
            int ci  = e / 120;
            int hbase = h0 - 4 + g * 4;       // aligned chunk of 4 h-values
            unsigned short b0 = 0, b1 = 0, b2 = 0, b3 = 0;
            if (hbase >= 0 && hbase <= 92) {
                ushort4 vv = *(const ushort4*)(basep
                    + (size_t)(imgbase + w) * LFV_IMG
                    + (size_t)ci * 480 + uin * 96 + hbase);
                b0 = vv.x; b1 = vv.y; b2 = vv.z; b3 = vv.w;
            }
            int sbase = (w*5 + uin) * 18;
            int hp0 = g*4 - 3;                // hp of element 0 (in [-3, 17])
            int cch = ci >> 3, clo = ci & 7;
            if (hp0 >= 0) {                               // hp0 <= 17 always
                int s = sbase + hp0;
                ins[s][((cch ^ (s & 7)) << 3) | clo] = b0;
            }
            if (hp0 + 1 >= 0 && hp0 + 1 < 18) {
                int s = sbase + hp0 + 1;
                ins[s][((cch ^ (s & 7)) << 3) | clo] = b1;
            }
            if (hp0 + 2 >= 0 && hp0 + 2 < 18) {
                int s = sbase + hp0 + 2;
                ins[s][((cch ^ (s & 7)) << 3) | clo] = b2;
            }
            if (hp0 + 3 < 18) {                           // hp0+3 >= 0 always
                int s = sbase + hp0 + 3;
                ins[s][((cch ^ (s & 7)) << 3) | clo] = b3;
            }
        }
        __syncthreads();

        // compute: K-steps (du,dh,kk); B-frag per u feeds 4 co-frag MFMAs
        for (int du = 0; du < 3; ++du) {
#pragma unroll
            for (int dh = 0; dh < 3; ++dh)
#pragma unroll
            for (int kk = 0; kk < 2; ++kk) {
                const unsigned short* wp = w2h + cc*576 + (du*3 + dh)*64
                                         + kk*32 + hi*8 + (size_t)l15*1152;
                i32x4 a0 = *(const i32x4*)(wp);
                i32x4 a1f = *(const i32x4*)(wp + 16*1152);
                i32x4 a2 = *(const i32x4*)(wp + 32*1152);
                i32x4 a3 = *(const i32x4*)(wp + 48*1152);
#pragma unroll
                for (int u = 0; u < 5; ++u) {
                    int uin = u + du - 1;
                    if (uin < 0 || uin > 4) continue;   // u-halo: exact skip
                    int s = (wl*5 + uin)*18 + hl + dh;
                    i32x4 bv = *(const i32x4*)&ins[s][((kk*4 + hi) ^ (s & 7)) << 3];
                    mfma_bf16_16x16x32(acc[u][0], a0, bv);
                    mfma_bf16_16x16x32(acc[u][1], a1f, bv);
                    mfma_bf16_16x16x32(acc[u][2], a2, bv);
                    mfma_bf16_16x16x32(acc[u][3], a3, bv);
                }
            }
        }
        if (!cc) __syncthreads();   // protect ins reuse before second stage
    }
#pragma unroll
    for (int u = 0; u < 5; ++u)
#pragma unroll
        for (int j = 0; j < 4; ++j)
            asm volatile("s_nop 7\ns_nop 7" : "+v"(acc[u][j]));

    // leaky + permuted store: out[(n*25+u*5+v)][co][h0+hl][w0+wl]
    int n = nv / 5, v = nv % 5;
#pragma unroll
    for (int u = 0; u < 5; ++u) {
        size_t ob = (size_t)((n*25 + u*5 + v) * 64) * IMG_HW
                  + (size_t)(h0 + hl) * 96 + w0 + wl;
#pragma unroll
        for (int j = 0; j < 4; ++j) {
#pragma unroll
            for (int rg = 0; rg < 4; ++rg) {
                int co = j*16 + hi*4 + rg;
                float x = acc[u][j][rg];
                x = x > 0.f ? x : 0.1f * x;
                outp[ob + (size_t)co * IMG_HW] = x;
            }
        }
    }
}

// ---------------------------------------------------------------------------
extern "C" void kernel_launch(void* const* d_in, const int* in_sizes, int n_in,
                              void* d_out, int out_size, void* d_ws, size_t ws_size,
                              hipStream_t stream) {
    const float* lf_fea = (const float*)d_in[0];
    const float* w1     = (const float*)d_in[1];
    const float* w2     = (const float*)d_in[2];
    float* outp = (float*)d_out;

    char* ws = (char*)d_ws;
    // ws layout (bytes), end 228,672,000 (< proven 258 MB footprint):
    //   lfVh :  58,982,400 @ 0                       (bf16)
    //   lfG  :  58,982,400 @  58,982,400             (bf16, gather-optimal)
    //   a1h/Gpart union     @ 117,964,800, size 88,473,600
    //     (Gpart written k2a, read k2b, dead before k4 writes a1h)
    //   dist :  22,118,400 @ 206,438,400             (w2h/w1h alias after k3)
    //   sq   :      46,080 @ 228,556,800
    //   idx  :      69,120 @ 228,602,880   (end 228,672,000)
    unsigned short* lfVh = (unsigned short*)(ws);
    unsigned short* lfG  = (unsigned short*)(ws + 58982400ull);
    unsigned short* a1h  = (unsigned short*)(ws + 117964800ull);
    float* Gpart = (float*)(ws + 117964800ull);   // aliases a1h (dead first)
    float* dist  = (float*)(ws + 206438400ull);
    float* sq    = (float*)(ws + 228556800ull);
    int*   idx   = (int*)  (ws + 228602880ull);
    unsigned short* w2h = (unsigned short*)(ws + 206438400ull);  // reuses dist
    unsigned short* w1h = (unsigned short*)(ws + 206438400ull + 147456ull);

    hipLaunchKernelGGL(k0_lfv,   dim3(3200), dim3(256), 0, stream, lf_fea, lfVh);
    hipLaunchKernelGGL(k0g_pack, dim3(2400), dim3(256), 0, stream, lf_fea, lfG);
    hipLaunchKernelGGL(k1_sq,    dim3(360),  dim3(256), 0, stream, lf_fea, sq);
    hipLaunchKernelGGL(k2a_gram, dim3(1440), dim3(256), 0, stream, lf_fea, Gpart);
    hipLaunchKernelGGL(k2b_dist, dim3(5400), dim3(256), 0, stream, Gpart, sq, dist);
    hipLaunchKernelGGL(k3_topk,  dim3(2880), dim3(256), 0, stream, dist, idx);
    hipLaunchKernelGGL(kw1_conv, dim3(96),   dim3(256), 0, stream, w1, w1h);
    hipLaunchKernelGGL(kw2_conv, dim3(288),  dim3(256), 0, stream, w2, w2h);
    hipLaunchKernelGGL(k4_conv1, dim3(5760), dim3(256), 0, stream, lfG, w1h, idx, a1h);
    hipLaunchKernelGGL(k5n_conv3,dim3(1440), dim3(256), 0, stream, lfVh, a1h, w2h, outp);
}

// Round 25
// 914.512 us; speedup vs baseline: 1.0176x; 1.0176x over previous
//
#include <hip/hip_runtime.h>
#include <stdint.h>

// Fixed problem config
#define NN   2
#define ANU  5
#define CH   64
#define HH   96
#define WW   96
#define KK   6
#define PSHh 8
#define PNHh 12
#define BB   (NN*PNHh)        // 24
#define PP   (ANU*WW)         // 480
#define CCD  (CH*ANU*PSHh)    // 2560
#define IMG_HW (HH*WW)            // 9216
#define IMG_STRIDE (CH*HH*WW)     // 589824 floats per input image
#define LFV_IMG (CH*ANU*HH)       // 30720 elems per (n,v,w) image in lfVh / a1h

typedef int   i32x4 __attribute__((ext_vector_type(4)));
typedef float f32x4 __attribute__((ext_vector_type(4)));

__device__ __forceinline__ unsigned short f2bf(float f) {
    unsigned int u = __float_as_uint(f);
    return (unsigned short)((u + 0x7FFFu + ((u >> 16) & 1u)) >> 16);
}

__device__ __forceinline__ void mfma_bf16_16x16x32(f32x4& d, i32x4 a, i32x4 b) {
    asm volatile("v_mfma_f32_16x16x32_bf16 %0, %1, %2, %0"
                 : "+v"(d) : "v"(a), "v"(b));
}

// ---------------------------------------------------------------------------
// K0: transpose lf_fea[(n,u,v)][c][h][w] -> lfVh[(n,v,w)][c][u][h] (bf16)
//     (r23 verbatim, passing)
// ---------------------------------------------------------------------------
__global__ __launch_bounds__(256) void k0_lfv(const float* __restrict__ lf_fea,
                                              unsigned short* __restrict__ lfVh) {
    int bc  = blockIdx.x;          // img*64 + c
    int img = bc >> 6;
    int c   = bc & 63;
    int n = img / 25, r = img % 25, u = r / 5, v = r % 5;
    const float* src = lf_fea + (size_t)bc * IMG_HW;
    __shared__ float tile[96][97];
    for (int e = threadIdx.x; e < 96*96; e += 256) {
        int h = e / 96, w = e % 96;
        tile[h][w] = src[e];
    }
    __syncthreads();
    size_t base = (size_t)((n*5 + v)*96) * LFV_IMG + (size_t)c*480 + u*96;
    for (int e = threadIdx.x; e < 96*96; e += 256) {
        int w = e / 96, h = e % 96;
        lfVh[base + (size_t)w * LFV_IMG + h] = f2bf(tile[h][w]);
    }
}

// ---------------------------------------------------------------------------
// K0g: pack lf_fea -> lfG[(n,pnh)][p=(v,w)][c][u][psh] (bf16, gather-optimal)
//      (r23 verbatim, passing)
// ---------------------------------------------------------------------------
__global__ __launch_bounds__(256) void k0g_pack(const float* __restrict__ lf,
                                                unsigned short* __restrict__ lfG) {
    int blk = blockIdx.x;            // ((img*12 + pnh)*4 + ct), grid 2400
    int ct = blk & 3; int r = blk >> 2;
    int pnh = r % 12, img = r / 12;
    int n = img / 25, rr = img % 25, u = rr / 5, v = rr % 5;
    int c0 = ct * 16;
    __shared__ float tile[16][8][97];
    int t = threadIdx.x;
    const float* src = lf + (size_t)img * IMG_STRIDE + (size_t)c0 * IMG_HW + pnh*768;
#pragma unroll
    for (int i = 0; i < 12; ++i) {
        int e = i*256 + t;           // 3072 float4
        int ci = e / 192, r2 = e % 192, psh = r2 / 24, q2 = r2 % 24;
        float4 vv = *(const float4*)(src + (size_t)ci*IMG_HW + psh*96 + q2*4);
        tile[ci][psh][q2*4+0]=vv.x; tile[ci][psh][q2*4+1]=vv.y;
        tile[ci][psh][q2*4+2]=vv.z; tile[ci][psh][q2*4+3]=vv.w;
    }
    __syncthreads();
    size_t ob = ((size_t)((n*12+pnh)*480 + v*96)) * 2560 + c0*40 + u*8;
#pragma unroll
    for (int i = 0; i < 24; ++i) {
        int e = i*256 + t;           // 6144 units = (w, ci, psh-pair)
        int w = e >> 6, r2 = e & 63, ci = r2 >> 2, pp = r2 & 3;
        size_t off = ob + (size_t)w*2560 + ci*40 + pp*2;
        lfG[off]     = f2bf(tile[ci][pp*2][w]);
        lfG[off + 1] = f2bf(tile[ci][pp*2+1][w]);
    }
}

// ---------------------------------------------------------------------------
// K1: sq[b][p] (fp64 accumulate), 8-way column split per row; 360 blocks
// ---------------------------------------------------------------------------
__global__ __launch_bounds__(256) void k1_sq(const float* __restrict__ lf_fea,
                                             float* __restrict__ sq) {
    int t = threadIdx.x;
    int row = blockIdx.x * 32 + (t & 31);      // 0..11519
    int cp = t >> 5;                           // 0..7
    int b = row / PP, p = row % PP;
    int n = b / PNHh, pnh = b % PNHh;
    int v = p / WW, w = p % WW;
    double acc = 0.0;
    for (int ci = 0; ci < 8; ++ci) {
        int c = cp * 8 + ci;
        for (int u = 0; u < 5; ++u) {
            const float* s = lf_fea + ((size_t)((n*25 + u*5 + v)*64 + c)) * IMG_HW
                           + pnh*8*96 + w;
#pragma unroll
            for (int psh = 0; psh < 8; ++psh) {
                float x = s[psh*96];
                acc += (double)x * (double)x;
            }
        }
    }
    __shared__ double red[256];
    red[t] = acc;
    __syncthreads();
    if (t < 32) {
        double ss = 0.0;
#pragma unroll
        for (int j = 0; j < 8; ++j) ss += red[j * 32 + t];
        sq[blockIdx.x * 32 + t] = (float)ss;
    }
}

// ---------------------------------------------------------------------------
// K2a: partial Gram, symmetric (vr<=vc), K-split 4; grid 1440.
//      r23 staging structure (direct load->LDS, low VGPR) + r24's verified
//      bank-conflict fix: col rotation w = sw + 8*((j+sr)%12) spreads writes
//      over 32 banks. LDS contents and summation order BIT-IDENTICAL to r23.
// ---------------------------------------------------------------------------
__global__ __launch_bounds__(256) void k2a_gram(const float* __restrict__ lf_fea,
                                                float* __restrict__ Gpart) {
    const int VRt[15] = {0,0,0,0,0,1,1,1,1,2,2,2,3,3,4};
    const int VCt[15] = {0,1,2,3,4,1,2,3,4,2,3,4,3,4,4};
    int blk = blockIdx.x;            // b*60 + pr*4 + ks
    int b  = blk / 60;
    int r0 = blk % 60;
    int pr = r0 / 4, ks = r0 % 4;
    int vr = VRt[pr], vc = VCt[pr];
    int n = b / PNHh, pnh = b % PNHh;

    __shared__ float As[32][96];
    __shared__ float Bs[32][96];

    int t  = threadIdx.x;
    int tx = t & 31, ty = t >> 5;    // 32 x 8 compute tiling
    int sr = t >> 3, sw = t & 7;     // staging: row 0..31, col-base 0..7
    float acc[12][3] = {};

    int kbase = ks * 640;
    for (int kc0 = kbase; kc0 < kbase + 640; kc0 += 32) {
        {
            int cc = kc0 + sr;
            int c = cc / 40, r2 = cc % 40, u = r2 >> 3, psh = r2 & 7;
            size_t off = ((size_t)((n*25 + u*5)*64 + c)) * IMG_HW + (pnh*8 + psh)*96;
            const float* pa = lf_fea + off + (size_t)vr * IMG_STRIDE;
            const float* pb = lf_fea + off + (size_t)vc * IMG_STRIDE;
#pragma unroll
            for (int j = 0; j < 12; ++j) {
                int w = sw + 8 * ((j + sr) % 12);   // rotated: 32-bank spread
                As[sr][w] = pa[w];
                Bs[sr][w] = pb[w];
            }
        }
        __syncthreads();
        float accC[12][3] = {};
#pragma unroll
        for (int kc = 0; kc < 32; ++kc) {
            float a[12], bq[3];
            *(float4*)&a[0] = *(const float4*)&As[kc][ty*12 + 0];
            *(float4*)&a[4] = *(const float4*)&As[kc][ty*12 + 4];
            *(float4*)&a[8] = *(const float4*)&As[kc][ty*12 + 8];
#pragma unroll
            for (int j = 0; j < 3; ++j) bq[j] = Bs[kc][tx*3 + j];
#pragma unroll
            for (int i = 0; i < 12; ++i)
#pragma unroll
                for (int j = 0; j < 3; ++j)
                    accC[i][j] = fmaf(a[i], bq[j], accC[i][j]);
        }
#pragma unroll
        for (int i = 0; i < 12; ++i)
#pragma unroll
            for (int j = 0; j < 3; ++j)
                acc[i][j] += accC[i][j];
        __syncthreads();
    }

    size_t gbase = ((size_t)(ks*600 + b*25 + vr*5 + vc)) * 9216;
#pragma unroll
    for (int i = 0; i < 12; ++i)
#pragma unroll
        for (int j = 0; j < 3; ++j)
            Gpart[gbase + (ty*12 + i)*96 + tx*3 + j] = acc[i][j];

    if (vr != vc) {
        size_t gbt = ((size_t)(ks*600 + b*25 + vc*5 + vr)) * 9216;
#pragma unroll
        for (int i = 0; i < 12; ++i)
#pragma unroll
            for (int j = 0; j < 3; ++j)
                Gpart[gbt + (tx*3 + j)*96 + ty*12 + i] = acc[i][j];
    }
}

// ---------------------------------------------------------------------------
// K2b: dist[b][p][q] = sq_p + sq_q - 2 * sum_ks Gpart   (r23 verbatim)
// ---------------------------------------------------------------------------
__global__ __launch_bounds__(256) void k2b_dist(const float* __restrict__ Gpart,
                                                const float* __restrict__ sq,
                                                float* __restrict__ dist) {
    int tid = blockIdx.x * 256 + threadIdx.x;   // grid 5400: exactly 1,382,400
    int b = tid / 57600;
    int r = tid % 57600;
    int p = r / 120, qt = r % 120;
    int vr = p / 96, pl = p % 96;
    int vc = qt / 24;
    int ql4 = (qt % 24) * 4;

    size_t tb = ((size_t)(b*25 + vr*5 + vc)) * 9216 + pl*96 + ql4;
    float4 g0 = *(const float4*)(Gpart + tb);
    float4 g1 = *(const float4*)(Gpart + tb +  600ull*9216);
    float4 g2 = *(const float4*)(Gpart + tb + 1200ull*9216);
    float4 g3 = *(const float4*)(Gpart + tb + 1800ull*9216);
    float gx = g0.x + g1.x + g2.x + g3.x;
    float gy = g0.y + g1.y + g2.y + g3.y;
    float gz = g0.z + g1.z + g2.z + g3.z;
    float gw = g0.w + g1.w + g2.w + g3.w;

    float  sqp = sq[b*480 + p];
    float4 sqq = *(const float4*)(sq + b*480 + vc*96 + ql4);
    float4 d;
    d.x = sqp + sqq.x - 2.0f * gx;
    d.y = sqp + sqq.y - 2.0f * gy;
    d.z = sqp + sqq.z - 2.0f * gz;
    d.w = sqp + sqq.w - 2.0f * gw;
    *(float4*)(dist + (size_t)b*230400 + (size_t)p*480 + vc*96 + ql4) = d;
}

// ---------------------------------------------------------------------------
// K3: per-row top-6  (passing, verbatim)
// ---------------------------------------------------------------------------
__global__ __launch_bounds__(256) void k3_topk(const float* __restrict__ dist,
                                               int* __restrict__ idx) {
    int wid  = (blockIdx.x * 256 + threadIdx.x) >> 6;  // global wave id
    int lane = threadIdx.x & 63;
    int b = wid / PP, p = wid % PP;
    const float* row = dist + (size_t)b * PP * PP + (size_t)p * PP;

    unsigned long long key[8];
#pragma unroll
    for (int j = 0; j < 8; ++j) {
        int q = j*64 + lane;
        if (q < PP) {
            unsigned int f = __float_as_uint(row[q]);
            unsigned int mono = f ^ ((f & 0x80000000u) ? 0xFFFFFFFFu : 0x80000000u);
            key[j] = ((unsigned long long)mono << 32) | (unsigned int)q;
        } else {
            key[j] = ~0ull;
        }
    }
    int* outp = idx + ((size_t)b*PP + p) * KK;
    for (int k = 0; k < KK; ++k) {
        unsigned long long m = key[0];
#pragma unroll
        for (int j = 1; j < 8; ++j) m = (key[j] < m) ? key[j] : m;
        for (int s = 1; s < 64; s <<= 1) {
            unsigned long long o = __shfl_xor(m, s, 64);
            m = (o < m) ? o : m;
        }
        if (lane == 0) outp[k] = (int)(m & 0xFFFFFFFFu);
#pragma unroll
        for (int j = 0; j < 8; ++j) if (key[j] == m) key[j] = ~0ull;
    }
}

// ---------------------------------------------------------------------------
// kw1: w1 -> bf16 flat copy w1h[co][k*64+c]  (passing, verbatim)
// ---------------------------------------------------------------------------
__global__ __launch_bounds__(256) void kw1_conv(const float* __restrict__ w1,
                                                unsigned short* __restrict__ w1h) {
    int e = blockIdx.x * 256 + threadIdx.x;   // 24576 total, grid 96
    if (e < 24576) w1h[e] = f2bf(w1[e]);
}

// ---------------------------------------------------------------------------
// kw2: reorder w2 -> bf16 w2h[co][cc][tap][ci64] (passing, verbatim)
// ---------------------------------------------------------------------------
__global__ __launch_bounds__(256) void kw2_conv(const float* __restrict__ w2,
                                                unsigned short* __restrict__ w2h) {
    int e = blockIdx.x * 256 + threadIdx.x;   // 73728 total
    if (e < 73728) {
        int co = e / 1152, r = e % 1152;
        int cc = r / 576, r2 = r % 576;
        int tap = r2 / 64, ci_l = r2 % 64;
        w2h[e] = f2bf(w2[co*1152 + (cc*64 + ci_l)*9 + tap]);
    }
}

// ---------------------------------------------------------------------------
// K4: gather + 1x1 conv via inline-asm MFMA  (r23 verbatim, passing)
// ---------------------------------------------------------------------------
__global__ __launch_bounds__(256) void k4_conv1(const unsigned short* __restrict__ lfG,
                                                const unsigned short* __restrict__ w1h,
                                                const int* __restrict__ idxg,
                                                unsigned short* __restrict__ a1h) {
    int blk = blockIdx.x;            // b*240 + ptile
    int b = blk / 240, ptile = blk % 240;
    int n = b / PNHh, pnh = b % PNHh;
    int p0 = ptile * 2;

    __shared__ unsigned short Bs[80][384];   // [col][swizzled krow] bf16
    __shared__ int idxs[12];

    int t = threadIdx.x;
    if (t < 12) idxs[t] = idxg[(b*PP + p0 + t/6)*KK + (t % 6)];
    __syncthreads();

    // stage: 3840 units of 16B; unit = (pl, k, m); m -> (c = m/5, u = m%5)
    for (int i = 0; i < 15; ++i) {
        int e = i * 256 + t;         // 3840 exactly
        int pl = e / 1920, r = e % 1920;
        int k = r / 320, m = r % 320;
        int c = m / 5, u = m % 5;
        int q = idxs[pl*6 + k];
        i32x4 vv = *(const i32x4*)(lfG + ((size_t)(b*480 + q))*2560 + m*8);
        int colbase = pl*40 + u*8;   // multiple of 8
        int krow = k*64 + c;
        int kc = krow >> 3, kl = krow & 7;
        int kbase = kc & ~7, klo = kc & 7;
#pragma unroll
        for (int j = 0; j < 4; ++j) {
            unsigned int d = (unsigned int)vv[j];
            int j0 = 2*j, j1 = 2*j + 1;
            Bs[colbase + j0][((kbase | (klo ^ j0)) << 3) | kl] =
                (unsigned short)(d & 0xFFFFu);
            Bs[colbase + j1][((kbase | (klo ^ j1)) << 3) | kl] =
                (unsigned short)(d >> 16);
        }
    }
    __syncthreads();

    int lane = t & 63, wv = t >> 6;
    int l15 = lane & 15, hi = lane >> 4;
    int co0 = wv * 16;
    f32x4 acc[5] = {};
#pragma unroll
    for (int f = 0; f < 5; ++f)
        asm volatile("s_nop 1" : "+v"(acc[f]));

    const unsigned short* ap = w1h + (size_t)(co0 + l15) * 384 + hi * 8;
    for (int ks = 0; ks < 12; ++ks) {
        i32x4 a = *(const i32x4*)(ap + ks * 32);
        asm volatile("s_nop 1" : "+v"(a));
#pragma unroll
        for (int f = 0; f < 5; ++f) {
            int col = f * 16 + l15;
            int ch = ks * 4 + hi;            // chunk 0..47
            int chs = (ch & ~7) | ((ch & 7) ^ (col & 7));
            i32x4 bv = *(const i32x4*)&Bs[col][chs << 3];
            mfma_bf16_16x16x32(acc[f], a, bv);
        }
    }
#pragma unroll
    for (int f = 0; f < 5; ++f)
        asm volatile("s_nop 7\ns_nop 7" : "+v"(acc[f]));

    // epilogue: leaky + bf16 u16 stores; D map: col=lane&15, row=hi*4+reg
#pragma unroll
    for (int f = 0; f < 5; ++f) {
        int col = f * 16 + l15;
        int pg = p0 + col / 40, rr = col % 40;
        int u = rr >> 3, psh = rr & 7;
        size_t base = (size_t)((n*5 + pg/96)*96 + (pg%96)) * LFV_IMG
                    + (size_t)u * 96 + pnh*8 + psh;
#pragma unroll
        for (int rg = 0; rg < 4; ++rg) {
            float x = acc[f][rg];
            x = x > 0.f ? x : 0.1f * x;
            a1h[base + (size_t)(co0 + hi*4 + rg) * 480] = f2bf(x);
        }
    }
}

// ---------------------------------------------------------------------------
// K5n: 3x3 conv via inline-asm MFMA, u-fused tile  (r23 verbatim, passing)
// ---------------------------------------------------------------------------
__global__ __launch_bounds__(256) void k5n_conv3(const unsigned short* __restrict__ lfVh,
                                                 const unsigned short* __restrict__ a1h,
                                                 const unsigned short* __restrict__ w2h,
                                                 float* __restrict__ outp) {
    int blk = blockIdx.x;             // grid 1440 = nv*144 + wt*6 + ht
    int ht = blk % 6;  int r = blk / 6;
    int wt = r % 24;   int nv = r / 24;    // nv = n*5 + v
    int w0 = wt * 4, h0 = ht * 16;
    int imgbase = nv * 96 + w0;

    __shared__ unsigned short ins[360][64];   // 46,080 B

    int t = threadIdx.x;
    int lane = t & 63, wv = t >> 6, l15 = lane & 15, hi = lane >> 4;
    int wl = l15 & 3;                 // output w within tile
    int hl = wv * 4 + (l15 >> 2);     // output h within tile (wave-split)

    f32x4 acc[5][4] = {};
#pragma unroll
    for (int u = 0; u < 5; ++u)
#pragma unroll
        for (int j = 0; j < 4; ++j)
            asm volatile("s_nop 1" : "+v"(acc[u][j]));

    for (int cc = 0; cc < 2; ++cc) {
        const unsigned short* basep = cc ? a1h : lfVh;
        if (cc) __syncthreads();
        // stage: e = (ci, uin, w, g): 4 h-values, b16 scatter with guards
        for (int i = 0; i < 30; ++i) {
            int e = i * 256 + t;              // 7680 = 64*5*4*6
            int g   = e % 6;
            int w   = (e / 6) & 3;
            int uin = (e / 24) % 5;
            int ci  = e / 120;
            int hbase = h0 - 4 + g * 4;       // aligned chunk of 4 h-values
            unsigned short b0 = 0, b1 = 0, b2 = 0, b3 = 0;
            if (hbase >= 0 && hbase <= 92) {
                ushort4 vv = *(const ushort4*)(basep
                    + (size_t)(imgbase + w) * LFV_IMG
                    + (size_t)ci * 480 + uin * 96 + hbase);
                b0 = vv.x; b1 = vv.y; b2 = vv.z; b3 = vv.w;
            }
            int sbase = (w*5 + uin) * 18;
            int hp0 = g*4 - 3;                // hp of element 0 (in [-3, 17])
            int cch = ci >> 3, clo = ci & 7;
            if (hp0 >= 0) {                               // hp0 <= 17 always
                int s = sbase + hp0;
                ins[s][((cch ^ (s & 7)) << 3) | clo] = b0;
            }
            if (hp0 + 1 >= 0 && hp0 + 1 < 18) {
                int s = sbase + hp0 + 1;
                ins[s][((cch ^ (s & 7)) << 3) | clo] = b1;
            }
            if (hp0 + 2 >= 0 && hp0 + 2 < 18) {
                int s = sbase + hp0 + 2;
                ins[s][((cch ^ (s & 7)) << 3) | clo] = b2;
            }
            if (hp0 + 3 < 18) {                           // hp0+3 >= 0 always
                int s = sbase + hp0 + 3;
                ins[s][((cch ^ (s & 7)) << 3) | clo] = b3;
            }
        }
        __syncthreads();

        // compute: K-steps (du,dh,kk); B-frag per u feeds 4 co-frag MFMAs
        for (int du = 0; du < 3; ++du) {
#pragma unroll
            for (int dh = 0; dh < 3; ++dh)
#pragma unroll
            for (int kk = 0; kk < 2; ++kk) {
                const unsigned short* wp = w2h + cc*576 + (du*3 + dh)*64
                                         + kk*32 + hi*8 + (size_t)l15*1152;
                i32x4 a0 = *(const i32x4*)(wp);
                i32x4 a1f = *(const i32x4*)(wp + 16*1152);
                i32x4 a2 = *(const i32x4*)(wp + 32*1152);
                i32x4 a3 = *(const i32x4*)(wp + 48*1152);
#pragma unroll
                for (int u = 0; u < 5; ++u) {
                    int uin = u + du - 1;
                    if (uin < 0 || uin > 4) continue;   // u-halo: exact skip
                    int s = (wl*5 + uin)*18 + hl + dh;
                    i32x4 bv = *(const i32x4*)&ins[s][((kk*4 + hi) ^ (s & 7)) << 3];
                    mfma_bf16_16x16x32(acc[u][0], a0, bv);
                    mfma_bf16_16x16x32(acc[u][1], a1f, bv);
                    mfma_bf16_16x16x32(acc[u][2], a2, bv);
                    mfma_bf16_16x16x32(acc[u][3], a3, bv);
                }
            }
        }
        if (!cc) __syncthreads();   // protect ins reuse before second stage
    }
#pragma unroll
    for (int u = 0; u < 5; ++u)
#pragma unroll
        for (int j = 0; j < 4; ++j)
            asm volatile("s_nop 7\ns_nop 7" : "+v"(acc[u][j]));

    // leaky + permuted store: out[(n*25+u*5+v)][co][h0+hl][w0+wl]
    int n = nv / 5, v = nv % 5;
#pragma unroll
    for (int u = 0; u < 5; ++u) {
        size_t ob = (size_t)((n*25 + u*5 + v) * 64) * IMG_HW
                  + (size_t)(h0 + hl) * 96 + w0 + wl;
#pragma unroll
        for (int j = 0; j < 4; ++j) {
#pragma unroll
            for (int rg = 0; rg < 4; ++rg) {
                int co = j*16 + hi*4 + rg;
                float x = acc[u][j][rg];
                x = x > 0.f ? x : 0.1f * x;
                outp[ob + (size_t)co * IMG_HW] = x;
            }
        }
    }
}

// ---------------------------------------------------------------------------
extern "C" void kernel_launch(void* const* d_in, const int* in_sizes, int n_in,
                              void* d_out, int out_size, void* d_ws, size_t ws_size,
                              hipStream_t stream) {
    const float* lf_fea = (const float*)d_in[0];
    const float* w1     = (const float*)d_in[1];
    const float* w2     = (const float*)d_in[2];
    float* outp = (float*)d_out;

    char* ws = (char*)d_ws;
    // ws layout (bytes), end 228,672,000 (< proven 258 MB footprint):
    //   lfVh :  58,982,400 @ 0                       (bf16)
    //   lfG  :  58,982,400 @  58,982,400             (bf16, gather-optimal)
    //   a1h/Gpart union     @ 117,964,800, size 88,473,600
    //     (Gpart written k2a, read k2b, dead before k4 writes a1h)
    //   dist :  22,118,400 @ 206,438,400             (w2h/w1h alias after k3)
    //   sq   :      46,080 @ 228,556,800
    //   idx  :      69,120 @ 228,602,880   (end 228,672,000)
    unsigned short* lfVh = (unsigned short*)(ws);
    unsigned short* lfG  = (unsigned short*)(ws + 58982400ull);
    unsigned short* a1h  = (unsigned short*)(ws + 117964800ull);
    float* Gpart = (float*)(ws + 117964800ull);   // aliases a1h (dead first)
    float* dist  = (float*)(ws + 206438400ull);
    float* sq    = (float*)(ws + 228556800ull);
    int*   idx   = (int*)  (ws + 228602880ull);
    unsigned short* w2h = (unsigned short*)(ws + 206438400ull);  // reuses dist
    unsigned short* w1h = (unsigned short*)(ws + 206438400ull + 147456ull);

    hipLaunchKernelGGL(k0_lfv,   dim3(3200), dim3(256), 0, stream, lf_fea, lfVh);
    hipLaunchKernelGGL(k0g_pack, dim3(2400), dim3(256), 0, stream, lf_fea, lfG);
    hipLaunchKernelGGL(k1_sq,    dim3(360),  dim3(256), 0, stream, lf_fea, sq);
    hipLaunchKernelGGL(k2a_gram, dim3(1440), dim3(256), 0, stream, lf_fea, Gpart);
    hipLaunchKernelGGL(k2b_dist, dim3(5400), dim3(256), 0, stream, Gpart, sq, dist);
    hipLaunchKernelGGL(k3_topk,  dim3(2880), dim3(256), 0, stream, dist, idx);
    hipLaunchKernelGGL(kw1_conv, dim3(96),   dim3(256), 0, stream, w1, w1h);
    hipLaunchKernelGGL(kw2_conv, dim3(288),  dim3(256), 0, stream, w2, w2h);
    hipLaunchKernelGGL(k4_conv1, dim3(5760), dim3(256), 0, stream, lfG, w1h, idx, a1h);
    hipLaunchKernelGGL(k5n_conv3,dim3(1440), dim3(256), 0, stream, lfVh, a1h, w2h, outp);
}

// Round 26
// 826.872 us; speedup vs baseline: 1.1254x; 1.1060x over previous
//
#include <hip/hip_runtime.h>
#include <stdint.h>

// Fixed problem config
#define NN   2
#define ANU  5
#define CH   64
#define HH   96
#define WW   96
#define KK   6
#define PSHh 8
#define PNHh 12
#define BB   (NN*PNHh)        // 24
#define PP   (ANU*WW)         // 480
#define CCD  (CH*ANU*PSHh)    // 2560
#define IMG_HW (HH*WW)            // 9216
#define IMG_STRIDE (CH*HH*WW)     // 589824 floats per input image
#define LFV_IMG (CH*ANU*HH)       // 30720 elems per (n,v,w) image in lfVh / a1h

typedef int   i32x4 __attribute__((ext_vector_type(4)));
typedef float f32x4 __attribute__((ext_vector_type(4)));

__device__ __forceinline__ unsigned short f2bf(float f) {
    unsigned int u = __float_as_uint(f);
    return (unsigned short)((u + 0x7FFFu + ((u >> 16) & 1u)) >> 16);
}

__device__ __forceinline__ void mfma_bf16_16x16x32(f32x4& d, i32x4 a, i32x4 b) {
    asm volatile("v_mfma_f32_16x16x32_bf16 %0, %1, %2, %0"
                 : "+v"(d) : "v"(a), "v"(b));
}

// ---------------------------------------------------------------------------
// K0: transpose lf_fea[(n,u,v)][c][h][w] -> lfVh[(n,v,w)][c][u][h] (bf16)
//     (r23 verbatim, passing)
// ---------------------------------------------------------------------------
__global__ __launch_bounds__(256) void k0_lfv(const float* __restrict__ lf_fea,
                                              unsigned short* __restrict__ lfVh) {
    int bc  = blockIdx.x;          // img*64 + c
    int img = bc >> 6;
    int c   = bc & 63;
    int n = img / 25, r = img % 25, u = r / 5, v = r % 5;
    const float* src = lf_fea + (size_t)bc * IMG_HW;
    __shared__ float tile[96][97];
    for (int e = threadIdx.x; e < 96*96; e += 256) {
        int h = e / 96, w = e % 96;
        tile[h][w] = src[e];
    }
    __syncthreads();
    size_t base = (size_t)((n*5 + v)*96) * LFV_IMG + (size_t)c*480 + u*96;
    for (int e = threadIdx.x; e < 96*96; e += 256) {
        int w = e / 96, h = e % 96;
        lfVh[base + (size_t)w * LFV_IMG + h] = f2bf(tile[h][w]);
    }
}

// ---------------------------------------------------------------------------
// K0g: pack lf_fea -> lfG[(n,pnh)][p=(v,w)][c][u][psh] (bf16, gather-optimal)
//      (r23 verbatim, passing)
// ---------------------------------------------------------------------------
__global__ __launch_bounds__(256) void k0g_pack(const float* __restrict__ lf,
                                                unsigned short* __restrict__ lfG) {
    int blk = blockIdx.x;            // ((img*12 + pnh)*4 + ct), grid 2400
    int ct = blk & 3; int r = blk >> 2;
    int pnh = r % 12, img = r / 12;
    int n = img / 25, rr = img % 25, u = rr / 5, v = rr % 5;
    int c0 = ct * 16;
    __shared__ float tile[16][8][97];
    int t = threadIdx.x;
    const float* src = lf + (size_t)img * IMG_STRIDE + (size_t)c0 * IMG_HW + pnh*768;
#pragma unroll
    for (int i = 0; i < 12; ++i) {
        int e = i*256 + t;           // 3072 float4
        int ci = e / 192, r2 = e % 192, psh = r2 / 24, q2 = r2 % 24;
        float4 vv = *(const float4*)(src + (size_t)ci*IMG_HW + psh*96 + q2*4);
        tile[ci][psh][q2*4+0]=vv.x; tile[ci][psh][q2*4+1]=vv.y;
        tile[ci][psh][q2*4+2]=vv.z; tile[ci][psh][q2*4+3]=vv.w;
    }
    __syncthreads();
    size_t ob = ((size_t)((n*12+pnh)*480 + v*96)) * 2560 + c0*40 + u*8;
#pragma unroll
    for (int i = 0; i < 24; ++i) {
        int e = i*256 + t;           // 6144 units = (w, ci, psh-pair)
        int w = e >> 6, r2 = e & 63, ci = r2 >> 2, pp = r2 & 3;
        size_t off = ob + (size_t)w*2560 + ci*40 + pp*2;
        lfG[off]     = f2bf(tile[ci][pp*2][w]);
        lfG[off + 1] = f2bf(tile[ci][pp*2+1][w]);
    }
}

// ---------------------------------------------------------------------------
// K1: sq[b][p] (fp64 accumulate), 8-way column split per row; 360 blocks
// ---------------------------------------------------------------------------
__global__ __launch_bounds__(256) void k1_sq(const float* __restrict__ lf_fea,
                                             float* __restrict__ sq) {
    int t = threadIdx.x;
    int row = blockIdx.x * 32 + (t & 31);      // 0..11519
    int cp = t >> 5;                           // 0..7
    int b = row / PP, p = row % PP;
    int n = b / PNHh, pnh = b % PNHh;
    int v = p / WW, w = p % WW;
    double acc = 0.0;
    for (int ci = 0; ci < 8; ++ci) {
        int c = cp * 8 + ci;
        for (int u = 0; u < 5; ++u) {
            const float* s = lf_fea + ((size_t)((n*25 + u*5 + v)*64 + c)) * IMG_HW
                           + pnh*8*96 + w;
#pragma unroll
            for (int psh = 0; psh < 8; ++psh) {
                float x = s[psh*96];
                acc += (double)x * (double)x;
            }
        }
    }
    __shared__ double red[256];
    red[t] = acc;
    __syncthreads();
    if (t < 32) {
        double ss = 0.0;
#pragma unroll
        for (int j = 0; j < 8; ++j) ss += red[j * 32 + t];
        sq[blockIdx.x * 32 + t] = (float)ss;
    }
}

// ---------------------------------------------------------------------------
// K2a: partial Gram, symmetric (vr<=vc), K-split 4; grid 1440.
//      r23 staging structure + CHEAP group-of-4 rotation:
//      w = wr[j&3] + 32*(j>>2), wr[k] = sw + 8*((k + (sr&3)) & 3).
//      Per write instruction lanes span 32 banks (2-way, free); only 4
//      precomputed offsets -> no VGPR bloat (r24/r25's %12 rotation cost
//      44 VGPRs and halved occupancy). LDS contents and summation order
//      BIT-IDENTICAL to r23 -> zero top-k risk.
// ---------------------------------------------------------------------------
__global__ __launch_bounds__(256) void k2a_gram(const float* __restrict__ lf_fea,
                                                float* __restrict__ Gpart) {
    const int VRt[15] = {0,0,0,0,0,1,1,1,1,2,2,2,3,3,4};
    const int VCt[15] = {0,1,2,3,4,1,2,3,4,2,3,4,3,4,4};
    int blk = blockIdx.x;            // b*60 + pr*4 + ks
    int b  = blk / 60;
    int r0 = blk % 60;
    int pr = r0 / 4, ks = r0 % 4;
    int vr = VRt[pr], vc = VCt[pr];
    int n = b / PNHh, pnh = b % PNHh;

    __shared__ float As[32][96];
    __shared__ float Bs[32][96];

    int t  = threadIdx.x;
    int tx = t & 31, ty = t >> 5;    // 32 x 8 compute tiling
    int sr = t >> 3, sw = t & 7;     // staging: row 0..31, col-base 0..7
    int m  = sr & 3;
    int wr0 = sw + 8 * m;
    int wr1 = sw + 8 * ((m + 1) & 3);
    int wr2 = sw + 8 * ((m + 2) & 3);
    int wr3 = sw + 8 * ((m + 3) & 3);
    float acc[12][3] = {};

    int kbase = ks * 640;
    for (int kc0 = kbase; kc0 < kbase + 640; kc0 += 32) {
        {
            int cc = kc0 + sr;
            int c = cc / 40, r2 = cc % 40, u = r2 >> 3, psh = r2 & 7;
            size_t off = ((size_t)((n*25 + u*5)*64 + c)) * IMG_HW + (pnh*8 + psh)*96;
            const float* pa = lf_fea + off + (size_t)vr * IMG_STRIDE;
            const float* pb = lf_fea + off + (size_t)vc * IMG_STRIDE;
#pragma unroll
            for (int g = 0; g < 3; ++g) {
                int w0 = wr0 + 32*g, w1 = wr1 + 32*g;
                int w2 = wr2 + 32*g, w3 = wr3 + 32*g;
                As[sr][w0] = pa[w0];  Bs[sr][w0] = pb[w0];
                As[sr][w1] = pa[w1];  Bs[sr][w1] = pb[w1];
                As[sr][w2] = pa[w2];  Bs[sr][w2] = pb[w2];
                As[sr][w3] = pa[w3];  Bs[sr][w3] = pb[w3];
            }
        }
        __syncthreads();
        float accC[12][3] = {};
#pragma unroll
        for (int kc = 0; kc < 32; ++kc) {
            float a[12], bq[3];
            *(float4*)&a[0] = *(const float4*)&As[kc][ty*12 + 0];
            *(float4*)&a[4] = *(const float4*)&As[kc][ty*12 + 4];
            *(float4*)&a[8] = *(const float4*)&As[kc][ty*12 + 8];
#pragma unroll
            for (int j = 0; j < 3; ++j) bq[j] = Bs[kc][tx*3 + j];
#pragma unroll
            for (int i = 0; i < 12; ++i)
#pragma unroll
                for (int j = 0; j < 3; ++j)
                    accC[i][j] = fmaf(a[i], bq[j], accC[i][j]);
        }
#pragma unroll
        for (int i = 0; i < 12; ++i)
#pragma unroll
            for (int j = 0; j < 3; ++j)
                acc[i][j] += accC[i][j];
        __syncthreads();
    }

    size_t gbase = ((size_t)(ks*600 + b*25 + vr*5 + vc)) * 9216;
#pragma unroll
    for (int i = 0; i < 12; ++i)
#pragma unroll
        for (int j = 0; j < 3; ++j)
            Gpart[gbase + (ty*12 + i)*96 + tx*3 + j] = acc[i][j];

    if (vr != vc) {
        size_t gbt = ((size_t)(ks*600 + b*25 + vc*5 + vr)) * 9216;
#pragma unroll
        for (int i = 0; i < 12; ++i)
#pragma unroll
            for (int j = 0; j < 3; ++j)
                Gpart[gbt + (tx*3 + j)*96 + ty*12 + i] = acc[i][j];
    }
}

// ---------------------------------------------------------------------------
// K2b: dist[b][p][q] = sq_p + sq_q - 2 * sum_ks Gpart   (r23 verbatim)
// ---------------------------------------------------------------------------
__global__ __launch_bounds__(256) void k2b_dist(const float* __restrict__ Gpart,
                                                const float* __restrict__ sq,
                                                float* __restrict__ dist) {
    int tid = blockIdx.x * 256 + threadIdx.x;   // grid 5400: exactly 1,382,400
    int b = tid / 57600;
    int r = tid % 57600;
    int p = r / 120, qt = r % 120;
    int vr = p / 96, pl = p % 96;
    int vc = qt / 24;
    int ql4 = (qt % 24) * 4;

    size_t tb = ((size_t)(b*25 + vr*5 + vc)) * 9216 + pl*96 + ql4;
    float4 g0 = *(const float4*)(Gpart + tb);
    float4 g1 = *(const float4*)(Gpart + tb +  600ull*9216);
    float4 g2 = *(const float4*)(Gpart + tb + 1200ull*9216);
    float4 g3 = *(const float4*)(Gpart + tb + 1800ull*9216);
    float gx = g0.x + g1.x + g2.x + g3.x;
    float gy = g0.y + g1.y + g2.y + g3.y;
    float gz = g0.z + g1.z + g2.z + g3.z;
    float gw = g0.w + g1.w + g2.w + g3.w;

    float  sqp = sq[b*480 + p];
    float4 sqq = *(const float4*)(sq + b*480 + vc*96 + ql4);
    float4 d;
    d.x = sqp + sqq.x - 2.0f * gx;
    d.y = sqp + sqq.y - 2.0f * gy;
    d.z = sqp + sqq.z - 2.0f * gz;
    d.w = sqp + sqq.w - 2.0f * gw;
    *(float4*)(dist + (size_t)b*230400 + (size_t)p*480 + vc*96 + ql4) = d;
}

// ---------------------------------------------------------------------------
// K3: per-row top-6  (passing, verbatim)
// ---------------------------------------------------------------------------
__global__ __launch_bounds__(256) void k3_topk(const float* __restrict__ dist,
                                               int* __restrict__ idx) {
    int wid  = (blockIdx.x * 256 + threadIdx.x) >> 6;  // global wave id
    int lane = threadIdx.x & 63;
    int b = wid / PP, p = wid % PP;
    const float* row = dist + (size_t)b * PP * PP + (size_t)p * PP;

    unsigned long long key[8];
#pragma unroll
    for (int j = 0; j < 8; ++j) {
        int q = j*64 + lane;
        if (q < PP) {
            unsigned int f = __float_as_uint(row[q]);
            unsigned int mono = f ^ ((f & 0x80000000u) ? 0xFFFFFFFFu : 0x80000000u);
            key[j] = ((unsigned long long)mono << 32) | (unsigned int)q;
        } else {
            key[j] = ~0ull;
        }
    }
    int* outp = idx + ((size_t)b*PP + p) * KK;
    for (int k = 0; k < KK; ++k) {
        unsigned long long m = key[0];
#pragma unroll
        for (int j = 1; j < 8; ++j) m = (key[j] < m) ? key[j] : m;
        for (int s = 1; s < 64; s <<= 1) {
            unsigned long long o = __shfl_xor(m, s, 64);
            m = (o < m) ? o : m;
        }
        if (lane == 0) outp[k] = (int)(m & 0xFFFFFFFFu);
#pragma unroll
        for (int j = 0; j < 8; ++j) if (key[j] == m) key[j] = ~0ull;
    }
}

// ---------------------------------------------------------------------------
// kw1: w1 -> bf16 flat copy w1h[co][k*64+c]  (passing, verbatim)
// ---------------------------------------------------------------------------
__global__ __launch_bounds__(256) void kw1_conv(const float* __restrict__ w1,
                                                unsigned short* __restrict__ w1h) {
    int e = blockIdx.x * 256 + threadIdx.x;   // 24576 total, grid 96
    if (e < 24576) w1h[e] = f2bf(w1[e]);
}

// ---------------------------------------------------------------------------
// kw2: reorder w2 -> bf16 w2h[co][cc][tap][ci64] (passing, verbatim)
// ---------------------------------------------------------------------------
__global__ __launch_bounds__(256) void kw2_conv(const float* __restrict__ w2,
                                                unsigned short* __restrict__ w2h) {
    int e = blockIdx.x * 256 + threadIdx.x;   // 73728 total
    if (e < 73728) {
        int co = e / 1152, r = e % 1152;
        int cc = r / 576, r2 = r % 576;
        int tap = r2 / 64, ci_l = r2 % 64;
        w2h[e] = f2bf(w2[co*1152 + (cc*64 + ci_l)*9 + tap]);
    }
}

// ---------------------------------------------------------------------------
// K4: gather + 1x1 conv via inline-asm MFMA  (r23 verbatim, passing)
// ---------------------------------------------------------------------------
__global__ __launch_bounds__(256) void k4_conv1(const unsigned short* __restrict__ lfG,
                                                const unsigned short* __restrict__ w1h,
                                                const int* __restrict__ idxg,
                                                unsigned short* __restrict__ a1h) {
    int blk = blockIdx.x;            // b*240 + ptile
    int b = blk / 240, ptile = blk % 240;
    int n = b / PNHh, pnh = b % PNHh;
    int p0 = ptile * 2;

    __shared__ unsigned short Bs[80][384];   // [col][swizzled krow] bf16
    __shared__ int idxs[12];

    int t = threadIdx.x;
    if (t < 12) idxs[t] = idxg[(b*PP + p0 + t/6)*KK + (t % 6)];
    __syncthreads();

    // stage: 3840 units of 16B; unit = (pl, k, m); m -> (c = m/5, u = m%5)
    for (int i = 0; i < 15; ++i) {
        int e = i * 256 + t;         // 3840 exactly
        int pl = e / 1920, r = e % 1920;
        int k = r / 320, m = r % 320;
        int c = m / 5, u = m % 5;
        int q = idxs[pl*6 + k];
        i32x4 vv = *(const i32x4*)(lfG + ((size_t)(b*480 + q))*2560 + m*8);
        int colbase = pl*40 + u*8;   // multiple of 8
        int krow = k*64 + c;
        int kc = krow >> 3, kl = krow & 7;
        int kbase = kc & ~7, klo = kc & 7;
#pragma unroll
        for (int j = 0; j < 4; ++j) {
            unsigned int d = (unsigned int)vv[j];
            int j0 = 2*j, j1 = 2*j + 1;
            Bs[colbase + j0][((kbase | (klo ^ j0)) << 3) | kl] =
                (unsigned short)(d & 0xFFFFu);
            Bs[colbase + j1][((kbase | (klo ^ j1)) << 3) | kl] =
                (unsigned short)(d >> 16);
        }
    }
    __syncthreads();

    int lane = t & 63, wv = t >> 6;
    int l15 = lane & 15, hi = lane >> 4;
    int co0 = wv * 16;
    f32x4 acc[5] = {};
#pragma unroll
    for (int f = 0; f < 5; ++f)
        asm volatile("s_nop 1" : "+v"(acc[f]));

    const unsigned short* ap = w1h + (size_t)(co0 + l15) * 384 + hi * 8;
    for (int ks = 0; ks < 12; ++ks) {
        i32x4 a = *(const i32x4*)(ap + ks * 32);
        asm volatile("s_nop 1" : "+v"(a));
#pragma unroll
        for (int f = 0; f < 5; ++f) {
            int col = f * 16 + l15;
            int ch = ks * 4 + hi;            // chunk 0..47
            int chs = (ch & ~7) | ((ch & 7) ^ (col & 7));
            i32x4 bv = *(const i32x4*)&Bs[col][chs << 3];
            mfma_bf16_16x16x32(acc[f], a, bv);
        }
    }
#pragma unroll
    for (int f = 0; f < 5; ++f)
        asm volatile("s_nop 7\ns_nop 7" : "+v"(acc[f]));

    // epilogue: leaky + bf16 u16 stores; D map: col=lane&15, row=hi*4+reg
#pragma unroll
    for (int f = 0; f < 5; ++f) {
        int col = f * 16 + l15;
        int pg = p0 + col / 40, rr = col % 40;
        int u = rr >> 3, psh = rr & 7;
        size_t base = (size_t)((n*5 + pg/96)*96 + (pg%96)) * LFV_IMG
                    + (size_t)u * 96 + pnh*8 + psh;
#pragma unroll
        for (int rg = 0; rg < 4; ++rg) {
            float x = acc[f][rg];
            x = x > 0.f ? x : 0.1f * x;
            a1h[base + (size_t)(co0 + hi*4 + rg) * 480] = f2bf(x);
        }
    }
}

// ---------------------------------------------------------------------------
// K5n: 3x3 conv via inline-asm MFMA, u-fused tile  (r23 verbatim, passing)
// ---------------------------------------------------------------------------
__global__ __launch_bounds__(256) void k5n_conv3(const unsigned short* __restrict__ lfVh,
                                                 const unsigned short* __restrict__ a1h,
                                                 const unsigned short* __restrict__ w2h,
                                                 float* __restrict__ outp) {
    int blk = blockIdx.x;             // grid 1440 = nv*144 + wt*6 + ht
    int ht = blk % 6;  int r = blk / 6;
    int wt = r % 24;   int nv = r / 24;    // nv = n*5 + v
    int w0 = wt * 4, h0 = ht * 16;
    int imgbase = nv * 96 + w0;

    __shared__ unsigned short ins[360][64];   // 46,080 B

    int t = threadIdx.x;
    int lane = t & 63, wv = t >> 6, l15 = lane & 15, hi = lane >> 4;
    int wl = l15 & 3;                 // output w within tile
    int hl = wv * 4 + (l15 >> 2);     // output h within tile (wave-split)

    f32x4 acc[5][4] = {};
#pragma unroll
    for (int u = 0; u < 5; ++u)
#pragma unroll
        for (int j = 0; j < 4; ++j)
            asm volatile("s_nop 1" : "+v"(acc[u][j]));

    for (int cc = 0; cc < 2; ++cc) {
        const unsigned short* basep = cc ? a1h : lfVh;
        if (cc) __syncthreads();
        // stage: e = (ci, uin, w, g): 4 h-values, b16 scatter with guards
        for (int i = 0; i < 30; ++i) {
            int e = i * 256 + t;              // 7680 = 64*5*4*6
            int g   = e % 6;
            int w   = (e / 6) & 3;
            int uin = (e / 24) % 5;
            int ci  = e / 120;
            int hbase = h0 - 4 + g * 4;       // aligned chunk of 4 h-values
            unsigned short b0 = 0, b1 = 0, b2 = 0, b3 = 0;
            if (hbase >= 0 && hbase <= 92) {
                ushort4 vv = *(const ushort4*)(basep
                    + (size_t)(imgbase + w) * LFV_IMG
                    + (size_t)ci * 480 + uin * 96 + hbase);
                b0 = vv.x; b1 = vv.y; b2 = vv.z; b3 = vv.w;
            }
            int sbase = (w*5 + uin) * 18;
            int hp0 = g*4 - 3;                // hp of element 0 (in [-3, 17])
            int cch = ci >> 3, clo = ci & 7;
            if (hp0 >= 0) {                               // hp0 <= 17 always
                int s = sbase + hp0;
                ins[s][((cch ^ (s & 7)) << 3) | clo] = b0;
            }
            if (hp0 + 1 >= 0 && hp0 + 1 < 18) {
                int s = sbase + hp0 + 1;
                ins[s][((cch ^ (s & 7)) << 3) | clo] = b1;
            }
            if (hp0 + 2 >= 0 && hp0 + 2 < 18) {
                int s = sbase + hp0 + 2;
                ins[s][((cch ^ (s & 7)) << 3) | clo] = b2;
            }
            if (hp0 + 3 < 18) {                           // hp0+3 >= 0 always
                int s = sbase + hp0 + 3;
                ins[s][((cch ^ (s & 7)) << 3) | clo] = b3;
            }
        }
        __syncthreads();

        // compute: K-steps (du,dh,kk); B-frag per u feeds 4 co-frag MFMAs
        for (int du = 0; du < 3; ++du) {
#pragma unroll
            for (int dh = 0; dh < 3; ++dh)
#pragma unroll
            for (int kk = 0; kk < 2; ++kk) {
                const unsigned short* wp = w2h + cc*576 + (du*3 + dh)*64
                                         + kk*32 + hi*8 + (size_t)l15*1152;
                i32x4 a0 = *(const i32x4*)(wp);
                i32x4 a1f = *(const i32x4*)(wp + 16*1152);
                i32x4 a2 = *(const i32x4*)(wp + 32*1152);
                i32x4 a3 = *(const i32x4*)(wp + 48*1152);
#pragma unroll
                for (int u = 0; u < 5; ++u) {
                    int uin = u + du - 1;
                    if (uin < 0 || uin > 4) continue;   // u-halo: exact skip
                    int s = (wl*5 + uin)*18 + hl + dh;
                    i32x4 bv = *(const i32x4*)&ins[s][((kk*4 + hi) ^ (s & 7)) << 3];
                    mfma_bf16_16x16x32(acc[u][0], a0, bv);
                    mfma_bf16_16x16x32(acc[u][1], a1f, bv);
                    mfma_bf16_16x16x32(acc[u][2], a2, bv);
                    mfma_bf16_16x16x32(acc[u][3], a3, bv);
                }
            }
        }
        if (!cc) __syncthreads();   // protect ins reuse before second stage
    }
#pragma unroll
    for (int u = 0; u < 5; ++u)
#pragma unroll
        for (int j = 0; j < 4; ++j)
            asm volatile("s_nop 7\ns_nop 7" : "+v"(acc[u][j]));

    // leaky + permuted store: out[(n*25+u*5+v)][co][h0+hl][w0+wl]
    int n = nv / 5, v = nv % 5;
#pragma unroll
    for (int u = 0; u < 5; ++u) {
        size_t ob = (size_t)((n*25 + u*5 + v) * 64) * IMG_HW
                  + (size_t)(h0 + hl) * 96 + w0 + wl;
#pragma unroll
        for (int j = 0; j < 4; ++j) {
#pragma unroll
            for (int rg = 0; rg < 4; ++rg) {
                int co = j*16 + hi*4 + rg;
                float x = acc[u][j][rg];
                x = x > 0.f ? x : 0.1f * x;
                outp[ob + (size_t)co * IMG_HW] = x;
            }
        }
    }
}

// ---------------------------------------------------------------------------
extern "C" void kernel_launch(void* const* d_in, const int* in_sizes, int n_in,
                              void* d_out, int out_size, void* d_ws, size_t ws_size,
                              hipStream_t stream) {
    const float* lf_fea = (const float*)d_in[0];
    const float* w1     = (const float*)d_in[1];
    const float* w2     = (const float*)d_in[2];
    float* outp = (float*)d_out;

    char* ws = (char*)d_ws;
    // ws layout (bytes), end 228,672,000 (< proven 258 MB footprint):
    //   lfVh :  58,982,400 @ 0                       (bf16)
    //   lfG  :  58,982,400 @  58,982,400             (bf16, gather-optimal)
    //   a1h/Gpart union     @ 117,964,800, size 88,473,600
    //     (Gpart written k2a, read k2b, dead before k4 writes a1h)
    //   dist :  22,118,400 @ 206,438,400             (w2h/w1h alias after k3)
    //   sq   :      46,080 @ 228,556,800
    //   idx  :      69,120 @ 228,602,880   (end 228,672,000)
    unsigned short* lfVh = (unsigned short*)(ws);
    unsigned short* lfG  = (unsigned short*)(ws + 58982400ull);
    unsigned short* a1h  = (unsigned short*)(ws + 117964800ull);
    float* Gpart = (float*)(ws + 117964800ull);   // aliases a1h (dead first)
    float* dist  = (float*)(ws + 206438400ull);
    float* sq    = (float*)(ws + 228556800ull);
    int*   idx   = (int*)  (ws + 228602880ull);
    unsigned short* w2h = (unsigned short*)(ws + 206438400ull);  // reuses dist
    unsigned short* w1h = (unsigned short*)(ws + 206438400ull + 147456ull);

    hipLaunchKernelGGL(k0_lfv,   dim3(3200), dim3(256), 0, stream, lf_fea, lfVh);
    hipLaunchKernelGGL(k0g_pack, dim3(2400), dim3(256), 0, stream, lf_fea, lfG);
    hipLaunchKernelGGL(k1_sq,    dim3(360),  dim3(256), 0, stream, lf_fea, sq);
    hipLaunchKernelGGL(k2a_gram, dim3(1440), dim3(256), 0, stream, lf_fea, Gpart);
    hipLaunchKernelGGL(k2b_dist, dim3(5400), dim3(256), 0, stream, Gpart, sq, dist);
    hipLaunchKernelGGL(k3_topk,  dim3(2880), dim3(256), 0, stream, dist, idx);
    hipLaunchKernelGGL(kw1_conv, dim3(96),   dim3(256), 0, stream, w1, w1h);
    hipLaunchKernelGGL(kw2_conv, dim3(288),  dim3(256), 0, stream, w2, w2h);
    hipLaunchKernelGGL(k4_conv1, dim3(5760), dim3(256), 0, stream, lfG, w1h, idx, a1h);
    hipLaunchKernelGGL(k5n_conv3,dim3(1440), dim3(256), 0, stream, lfVh, a1h, w2h, outp);
}

// Round 27
// 823.162 us; speedup vs baseline: 1.1305x; 1.0045x over previous
//
#include <hip/hip_runtime.h>
#include <stdint.h>

// Fixed problem config
#define NN   2
#define ANU  5
#define CH   64
#define HH   96
#define WW   96
#define KK   6
#define PSHh 8
#define PNHh 12
#define BB   (NN*PNHh)        // 24
#define PP   (ANU*WW)         // 480
#define CCD  (CH*ANU*PSHh)    // 2560
#define IMG_HW (HH*WW)            // 9216
#define IMG_STRIDE (CH*HH*WW)     // 589824 floats per input image
#define LFV_IMG (CH*ANU*HH)       // 30720 elems per (n,v,w) image in lfVh / a1h

typedef int   i32x4 __attribute__((ext_vector_type(4)));
typedef float f32x4 __attribute__((ext_vector_type(4)));

__device__ __forceinline__ unsigned short f2bf(float f) {
    unsigned int u = __float_as_uint(f);
    return (unsigned short)((u + 0x7FFFu + ((u >> 16) & 1u)) >> 16);
}

__device__ __forceinline__ void mfma_bf16_16x16x32(f32x4& d, i32x4 a, i32x4 b) {
    asm volatile("v_mfma_f32_16x16x32_bf16 %0, %1, %2, %0"
                 : "+v"(d) : "v"(a), "v"(b));
}

// ---------------------------------------------------------------------------
// K0g: pack lf_fea -> lfG[(n,pnh)][p=(v,w)][c][u][psh] (bf16, gather-optimal)
//      AND lfVh[(n,v,w)][c][u][h] (bf16) from the SAME staged tile — merges
//      the old k0_lfv (whole-input re-read deleted). Values bit-identical:
//      same f2bf on the same fp32 elements. grid 2400 (r26 decomposition).
// ---------------------------------------------------------------------------
__global__ __launch_bounds__(256) void k0g_pack(const float* __restrict__ lf,
                                                unsigned short* __restrict__ lfG,
                                                unsigned short* __restrict__ lfVh) {
    int blk = blockIdx.x;            // ((img*12 + pnh)*4 + ct), grid 2400
    int ct = blk & 3; int r = blk >> 2;
    int pnh = r % 12, img = r / 12;
    int n = img / 25, rr = img % 25, u = rr / 5, v = rr % 5;
    int c0 = ct * 16;
    __shared__ float tile[16][8][97];
    int t = threadIdx.x;
    const float* src = lf + (size_t)img * IMG_STRIDE + (size_t)c0 * IMG_HW + pnh*768;
#pragma unroll
    for (int i = 0; i < 12; ++i) {
        int e = i*256 + t;           // 3072 float4
        int ci = e / 192, r2 = e % 192, psh = r2 / 24, q2 = r2 % 24;
        float4 vv = *(const float4*)(src + (size_t)ci*IMG_HW + psh*96 + q2*4);
        tile[ci][psh][q2*4+0]=vv.x; tile[ci][psh][q2*4+1]=vv.y;
        tile[ci][psh][q2*4+2]=vv.z; tile[ci][psh][q2*4+3]=vv.w;
    }
    __syncthreads();
    // lfG stores (r26 verbatim)
    size_t ob = ((size_t)((n*12+pnh)*480 + v*96)) * 2560 + c0*40 + u*8;
#pragma unroll
    for (int i = 0; i < 24; ++i) {
        int e = i*256 + t;           // 6144 units = (w, ci, psh-pair)
        int w = e >> 6, r2 = e & 63, ci = r2 >> 2, pp = r2 & 3;
        size_t off = ob + (size_t)w*2560 + ci*40 + pp*2;
        lfG[off]     = f2bf(tile[ci][pp*2][w]);
        lfG[off + 1] = f2bf(tile[ci][pp*2+1][w]);
    }
    // lfVh stores: lfVh[(n,v,w)][c0+ci][u][pnh*8+psh] = tile[ci][psh][w]
    size_t vb = (size_t)((n*5 + v)*96) * LFV_IMG + (size_t)c0*480 + u*96 + pnh*8;
#pragma unroll
    for (int i = 0; i < 48; ++i) {
        int e = i*256 + t;           // 12288 u16 stores = (w, ci, psh)
        int psh = e & 7, r3 = e >> 3;
        int ci = r3 & 15, w = r3 >> 4;
        lfVh[vb + (size_t)w*LFV_IMG + ci*480 + psh] = f2bf(tile[ci][psh][w]);
    }
}

// ---------------------------------------------------------------------------
// K1: sq[b][p] (fp64 accumulate), 8-way column split per row; 360 blocks
// ---------------------------------------------------------------------------
__global__ __launch_bounds__(256) void k1_sq(const float* __restrict__ lf_fea,
                                             float* __restrict__ sq) {
    int t = threadIdx.x;
    int row = blockIdx.x * 32 + (t & 31);      // 0..11519
    int cp = t >> 5;                           // 0..7
    int b = row / PP, p = row % PP;
    int n = b / PNHh, pnh = b % PNHh;
    int v = p / WW, w = p % WW;
    double acc = 0.0;
    for (int ci = 0; ci < 8; ++ci) {
        int c = cp * 8 + ci;
        for (int u = 0; u < 5; ++u) {
            const float* s = lf_fea + ((size_t)((n*25 + u*5 + v)*64 + c)) * IMG_HW
                           + pnh*8*96 + w;
#pragma unroll
            for (int psh = 0; psh < 8; ++psh) {
                float x = s[psh*96];
                acc += (double)x * (double)x;
            }
        }
    }
    __shared__ double red[256];
    red[t] = acc;
    __syncthreads();
    if (t < 32) {
        double ss = 0.0;
#pragma unroll
        for (int j = 0; j < 8; ++j) ss += red[j * 32 + t];
        sq[blockIdx.x * 32 + t] = (float)ss;
    }
}

// ---------------------------------------------------------------------------
// K2a: partial Gram, symmetric (vr<=vc), K-split 4; grid 1440  (r26 verbatim)
// ---------------------------------------------------------------------------
__global__ __launch_bounds__(256) void k2a_gram(const float* __restrict__ lf_fea,
                                                float* __restrict__ Gpart) {
    const int VRt[15] = {0,0,0,0,0,1,1,1,1,2,2,2,3,3,4};
    const int VCt[15] = {0,1,2,3,4,1,2,3,4,2,3,4,3,4,4};
    int blk = blockIdx.x;            // b*60 + pr*4 + ks
    int b  = blk / 60;
    int r0 = blk % 60;
    int pr = r0 / 4, ks = r0 % 4;
    int vr = VRt[pr], vc = VCt[pr];
    int n = b / PNHh, pnh = b % PNHh;

    __shared__ float As[32][96];
    __shared__ float Bs[32][96];

    int t  = threadIdx.x;
    int tx = t & 31, ty = t >> 5;    // 32 x 8 compute tiling
    int sr = t >> 3, sw = t & 7;     // staging: row 0..31, col-base 0..7
    int m  = sr & 3;
    int wr0 = sw + 8 * m;
    int wr1 = sw + 8 * ((m + 1) & 3);
    int wr2 = sw + 8 * ((m + 2) & 3);
    int wr3 = sw + 8 * ((m + 3) & 3);
    float acc[12][3] = {};

    int kbase = ks * 640;
    for (int kc0 = kbase; kc0 < kbase + 640; kc0 += 32) {
        {
            int cc = kc0 + sr;
            int c = cc / 40, r2 = cc % 40, u = r2 >> 3, psh = r2 & 7;
            size_t off = ((size_t)((n*25 + u*5)*64 + c)) * IMG_HW + (pnh*8 + psh)*96;
            const float* pa = lf_fea + off + (size_t)vr * IMG_STRIDE;
            const float* pb = lf_fea + off + (size_t)vc * IMG_STRIDE;
#pragma unroll
            for (int g = 0; g < 3; ++g) {
                int w0 = wr0 + 32*g, w1 = wr1 + 32*g;
                int w2 = wr2 + 32*g, w3 = wr3 + 32*g;
                As[sr][w0] = pa[w0];  Bs[sr][w0] = pb[w0];
                As[sr][w1] = pa[w1];  Bs[sr][w1] = pb[w1];
                As[sr][w2] = pa[w2];  Bs[sr][w2] = pb[w2];
                As[sr][w3] = pa[w3];  Bs[sr][w3] = pb[w3];
            }
        }
        __syncthreads();
        float accC[12][3] = {};
#pragma unroll
        for (int kc = 0; kc < 32; ++kc) {
            float a[12], bq[3];
            *(float4*)&a[0] = *(const float4*)&As[kc][ty*12 + 0];
            *(float4*)&a[4] = *(const float4*)&As[kc][ty*12 + 4];
            *(float4*)&a[8] = *(const float4*)&As[kc][ty*12 + 8];
#pragma unroll
            for (int j = 0; j < 3; ++j) bq[j] = Bs[kc][tx*3 + j];
#pragma unroll
            for (int i = 0; i < 12; ++i)
#pragma unroll
                for (int j = 0; j < 3; ++j)
                    accC[i][j] = fmaf(a[i], bq[j], accC[i][j]);
        }
#pragma unroll
        for (int i = 0; i < 12; ++i)
#pragma unroll
            for (int j = 0; j < 3; ++j)
                acc[i][j] += accC[i][j];
        __syncthreads();
    }

    size_t gbase = ((size_t)(ks*600 + b*25 + vr*5 + vc)) * 9216;
#pragma unroll
    for (int i = 0; i < 12; ++i)
#pragma unroll
        for (int j = 0; j < 3; ++j)
            Gpart[gbase + (ty*12 + i)*96 + tx*3 + j] = acc[i][j];

    if (vr != vc) {
        size_t gbt = ((size_t)(ks*600 + b*25 + vc*5 + vr)) * 9216;
#pragma unroll
        for (int i = 0; i < 12; ++i)
#pragma unroll
            for (int j = 0; j < 3; ++j)
                Gpart[gbt + (tx*3 + j)*96 + ty*12 + i] = acc[i][j];
    }
}

// ---------------------------------------------------------------------------
// K3f: per-row top-6, dist computed INLINE from Gpart + sq with the exact
//      k2b expression (sqp + sqq) - 2*(((g0+g1)+g2)+g3) -> bit-identical
//      keys -> identical indices. dist buffer and k2b launch deleted.
// ---------------------------------------------------------------------------
__global__ __launch_bounds__(256) void k3_topk(const float* __restrict__ Gpart,
                                               const float* __restrict__ sq,
                                               int* __restrict__ idx) {
    int wid  = (blockIdx.x * 256 + threadIdx.x) >> 6;  // global wave id
    int lane = threadIdx.x & 63;
    int b = wid / PP, p = wid % PP;
    int vr = p / 96, pl = p % 96;
    const float* gb = Gpart + ((size_t)(b*25 + vr*5)) * 9216 + pl*96;
    float sqp = sq[b*480 + p];

    unsigned long long key[8];
#pragma unroll
    for (int j = 0; j < 8; ++j) {
        int q = j*64 + lane;
        if (q < PP) {
            int vc = q / 96, ql = q % 96;
            size_t off = (size_t)vc * 9216 + ql;
            float g0 = gb[off];
            float g1 = gb[off +  600ull*9216];
            float g2 = gb[off + 1200ull*9216];
            float g3 = gb[off + 1800ull*9216];
            float gx = g0 + g1 + g2 + g3;
            float d  = sqp + sq[b*480 + q] - 2.0f * gx;
            unsigned int f = __float_as_uint(d);
            unsigned int mono = f ^ ((f & 0x80000000u) ? 0xFFFFFFFFu : 0x80000000u);
            key[j] = ((unsigned long long)mono << 32) | (unsigned int)q;
        } else {
            key[j] = ~0ull;
        }
    }
    int* outp = idx + ((size_t)b*PP + p) * KK;
    for (int k = 0; k < KK; ++k) {
        unsigned long long m = key[0];
#pragma unroll
        for (int j = 1; j < 8; ++j) m = (key[j] < m) ? key[j] : m;
        for (int s = 1; s < 64; s <<= 1) {
            unsigned long long o = __shfl_xor(m, s, 64);
            m = (o < m) ? o : m;
        }
        if (lane == 0) outp[k] = (int)(m & 0xFFFFFFFFu);
#pragma unroll
        for (int j = 0; j < 8; ++j) if (key[j] == m) key[j] = ~0ull;
    }
}

// ---------------------------------------------------------------------------
// kw1: w1 -> bf16 flat copy w1h[co][k*64+c]  (passing, verbatim)
// ---------------------------------------------------------------------------
__global__ __launch_bounds__(256) void kw1_conv(const float* __restrict__ w1,
                                                unsigned short* __restrict__ w1h) {
    int e = blockIdx.x * 256 + threadIdx.x;   // 24576 total, grid 96
    if (e < 24576) w1h[e] = f2bf(w1[e]);
}

// ---------------------------------------------------------------------------
// kw2: reorder w2 -> bf16 w2h[co][cc][tap][ci64] (passing, verbatim)
// ---------------------------------------------------------------------------
__global__ __launch_bounds__(256) void kw2_conv(const float* __restrict__ w2,
                                                unsigned short* __restrict__ w2h) {
    int e = blockIdx.x * 256 + threadIdx.x;   // 73728 total
    if (e < 73728) {
        int co = e / 1152, r = e % 1152;
        int cc = r / 576, r2 = r % 576;
        int tap = r2 / 64, ci_l = r2 % 64;
        w2h[e] = f2bf(w2[co*1152 + (cc*64 + ci_l)*9 + tap]);
    }
}

// ---------------------------------------------------------------------------
// K4: gather + 1x1 conv via inline-asm MFMA  (r26 verbatim, passing)
// ---------------------------------------------------------------------------
__global__ __launch_bounds__(256) void k4_conv1(const unsigned short* __restrict__ lfG,
                                                const unsigned short* __restrict__ w1h,
                                                const int* __restrict__ idxg,
                                                unsigned short* __restrict__ a1h) {
    int blk = blockIdx.x;            // b*240 + ptile
    int b = blk / 240, ptile = blk % 240;
    int n = b / PNHh, pnh = b % PNHh;
    int p0 = ptile * 2;

    __shared__ unsigned short Bs[80][384];   // [col][swizzled krow] bf16
    __shared__ int idxs[12];

    int t = threadIdx.x;
    if (t < 12) idxs[t] = idxg[(b*PP + p0 + t/6)*KK + (t % 6)];
    __syncthreads();

    // stage: 3840 units of 16B; unit = (pl, k, m); m -> (c = m/5, u = m%5)
    for (int i = 0; i < 15; ++i) {
        int e = i * 256 + t;         // 3840 exactly
        int pl = e / 1920, r = e % 1920;
        int k = r / 320, m = r % 320;
        int c = m / 5, u = m % 5;
        int q = idxs[pl*6 + k];
        i32x4 vv = *(const i32x4*)(lfG + ((size_t)(b*480 + q))*2560 + m*8);
        int colbase = pl*40 + u*8;   // multiple of 8
        int krow = k*64 + c;
        int kc = krow >> 3, kl = krow & 7;
        int kbase = kc & ~7, klo = kc & 7;
#pragma unroll
        for (int j = 0; j < 4; ++j) {
            unsigned int d = (unsigned int)vv[j];
            int j0 = 2*j, j1 = 2*j + 1;
            Bs[colbase + j0][((kbase | (klo ^ j0)) << 3) | kl] =
                (unsigned short)(d & 0xFFFFu);
            Bs[colbase + j1][((kbase | (klo ^ j1)) << 3) | kl] =
                (unsigned short)(d >> 16);
        }
    }
    __syncthreads();

    int lane = t & 63, wv = t >> 6;
    int l15 = lane & 15, hi = lane >> 4;
    int co0 = wv * 16;
    f32x4 acc[5] = {};
#pragma unroll
    for (int f = 0; f < 5; ++f)
        asm volatile("s_nop 1" : "+v"(acc[f]));

    const unsigned short* ap = w1h + (size_t)(co0 + l15) * 384 + hi * 8;
    for (int ks = 0; ks < 12; ++ks) {
        i32x4 a = *(const i32x4*)(ap + ks * 32);
        asm volatile("s_nop 1" : "+v"(a));
#pragma unroll
        for (int f = 0; f < 5; ++f) {
            int col = f * 16 + l15;
            int ch = ks * 4 + hi;            // chunk 0..47
            int chs = (ch & ~7) | ((ch & 7) ^ (col & 7));
            i32x4 bv = *(const i32x4*)&Bs[col][chs << 3];
            mfma_bf16_16x16x32(acc[f], a, bv);
        }
    }
#pragma unroll
    for (int f = 0; f < 5; ++f)
        asm volatile("s_nop 7\ns_nop 7" : "+v"(acc[f]));

    // epilogue: leaky + bf16 u16 stores; D map: col=lane&15, row=hi*4+reg
#pragma unroll
    for (int f = 0; f < 5; ++f) {
        int col = f * 16 + l15;
        int pg = p0 + col / 40, rr = col % 40;
        int u = rr >> 3, psh = rr & 7;
        size_t base = (size_t)((n*5 + pg/96)*96 + (pg%96)) * LFV_IMG
                    + (size_t)u * 96 + pnh*8 + psh;
#pragma unroll
        for (int rg = 0; rg < 4; ++rg) {
            float x = acc[f][rg];
            x = x > 0.f ? x : 0.1f * x;
            a1h[base + (size_t)(co0 + hi*4 + rg) * 480] = f2bf(x);
        }
    }
}

// ---------------------------------------------------------------------------
// K5n: 3x3 conv via inline-asm MFMA, u-fused tile  (r26 verbatim, passing)
// ---------------------------------------------------------------------------
__global__ __launch_bounds__(256) void k5n_conv3(const unsigned short* __restrict__ lfVh,
                                                 const unsigned short* __restrict__ a1h,
                                                 const unsigned short* __restrict__ w2h,
                                                 float* __restrict__ outp) {
    int blk = blockIdx.x;             // grid 1440 = nv*144 + wt*6 + ht
    int ht = blk % 6;  int r = blk / 6;
    int wt = r % 24;   int nv = r / 24;    // nv = n*5 + v
    int w0 = wt * 4, h0 = ht * 16;
    int imgbase = nv * 96 + w0;

    __shared__ unsigned short ins[360][64];   // 46,080 B

    int t = threadIdx.x;
    int lane = t & 63, wv = t >> 6, l15 = lane & 15, hi = lane >> 4;
    int wl = l15 & 3;                 // output w within tile
    int hl = wv * 4 + (l15 >> 2);     // output h within tile (wave-split)

    f32x4 acc[5][4] = {};
#pragma unroll
    for (int u = 0; u < 5; ++u)
#pragma unroll
        for (int j = 0; j < 4; ++j)
            asm volatile("s_nop 1" : "+v"(acc[u][j]));

    for (int cc = 0; cc < 2; ++cc) {
        const unsigned short* basep = cc ? a1h : lfVh;
        if (cc) __syncthreads();
        // stage: e = (ci, uin, w, g): 4 h-values, b16 scatter with guards
        for (int i = 0; i < 30; ++i) {
            int e = i * 256 + t;              // 7680 = 64*5*4*6
            int g   = e % 6;
            int w   = (e / 6) & 3;
            int uin = (e / 24) % 5;
            int ci  = e / 120;
            int hbase = h0 - 4 + g * 4;       // aligned chunk of 4 h-values
            unsigned short b0 = 0, b1 = 0, b2 = 0, b3 = 0;
            if (hbase >= 0 && hbase <= 92) {
                ushort4 vv = *(const ushort4*)(basep
                    + (size_t)(imgbase + w) * LFV_IMG
                    + (size_t)ci * 480 + uin * 96 + hbase);
                b0 = vv.x; b1 = vv.y; b2 = vv.z; b3 = vv.w;
            }
            int sbase = (w*5 + uin) * 18;
            int hp0 = g*4 - 3;                // hp of element 0 (in [-3, 17])
            int cch = ci >> 3, clo = ci & 7;
            if (hp0 >= 0) {                               // hp0 <= 17 always
                int s = sbase + hp0;
                ins[s][((cch ^ (s & 7)) << 3) | clo] = b0;
            }
            if (hp0 + 1 >= 0 && hp0 + 1 < 18) {
                int s = sbase + hp0 + 1;
                ins[s][((cch ^ (s & 7)) << 3) | clo] = b1;
            }
            if (hp0 + 2 >= 0 && hp0 + 2 < 18) {
                int s = sbase + hp0 + 2;
                ins[s][((cch ^ (s & 7)) << 3) | clo] = b2;
            }
            if (hp0 + 3 < 18) {                           // hp0+3 >= 0 always
                int s = sbase + hp0 + 3;
                ins[s][((cch ^ (s & 7)) << 3) | clo] = b3;
            }
        }
        __syncthreads();

        // compute: K-steps (du,dh,kk); B-frag per u feeds 4 co-frag MFMAs
        for (int du = 0; du < 3; ++du) {
#pragma unroll
            for (int dh = 0; dh < 3; ++dh)
#pragma unroll
            for (int kk = 0; kk < 2; ++kk) {
                const unsigned short* wp = w2h + cc*576 + (du*3 + dh)*64
                                         + kk*32 + hi*8 + (size_t)l15*1152;
                i32x4 a0 = *(const i32x4*)(wp);
                i32x4 a1f = *(const i32x4*)(wp + 16*1152);
                i32x4 a2 = *(const i32x4*)(wp + 32*1152);
                i32x4 a3 = *(const i32x4*)(wp + 48*1152);
#pragma unroll
                for (int u = 0; u < 5; ++u) {
                    int uin = u + du - 1;
                    if (uin < 0 || uin > 4) continue;   // u-halo: exact skip
                    int s = (wl*5 + uin)*18 + hl + dh;
                    i32x4 bv = *(const i32x4*)&ins[s][((kk*4 + hi) ^ (s & 7)) << 3];
                    mfma_bf16_16x16x32(acc[u][0], a0, bv);
                    mfma_bf16_16x16x32(acc[u][1], a1f, bv);
                    mfma_bf16_16x16x32(acc[u][2], a2, bv);
                    mfma_bf16_16x16x32(acc[u][3], a3, bv);
                }
            }
        }
        if (!cc) __syncthreads();   // protect ins reuse before second stage
    }
#pragma unroll
    for (int u = 0; u < 5; ++u)
#pragma unroll
        for (int j = 0; j < 4; ++j)
            asm volatile("s_nop 7\ns_nop 7" : "+v"(acc[u][j]));

    // leaky + permuted store: out[(n*25+u*5+v)][co][h0+hl][w0+wl]
    int n = nv / 5, v = nv % 5;
#pragma unroll
    for (int u = 0; u < 5; ++u) {
        size_t ob = (size_t)((n*25 + u*5 + v) * 64) * IMG_HW
                  + (size_t)(h0 + hl) * 96 + w0 + wl;
#pragma unroll
        for (int j = 0; j < 4; ++j) {
#pragma unroll
            for (int rg = 0; rg < 4; ++rg) {
                int co = j*16 + hi*4 + rg;
                float x = acc[u][j][rg];
                x = x > 0.f ? x : 0.1f * x;
                outp[ob + (size_t)co * IMG_HW] = x;
            }
        }
    }
}

// ---------------------------------------------------------------------------
extern "C" void kernel_launch(void* const* d_in, const int* in_sizes, int n_in,
                              void* d_out, int out_size, void* d_ws, size_t ws_size,
                              hipStream_t stream) {
    const float* lf_fea = (const float*)d_in[0];
    const float* w1     = (const float*)d_in[1];
    const float* w2     = (const float*)d_in[2];
    float* outp = (float*)d_out;

    char* ws = (char*)d_ws;
    // ws layout (bytes), end 228,672,000 (< proven 258 MB footprint):
    //   lfVh :  58,982,400 @ 0                       (bf16)
    //   lfG  :  58,982,400 @  58,982,400             (bf16, gather-optimal)
    //   a1h/Gpart union     @ 117,964,800, size 88,473,600
    //     (Gpart written k2a, read k3, dead before k4 writes a1h)
    //   w2h/w1h            @ 206,438,400             (old dist slot, now free)
    //   sq   :      46,080 @ 228,556,800
    //   idx  :      69,120 @ 228,602,880   (end 228,672,000)
    unsigned short* lfVh = (unsigned short*)(ws);
    unsigned short* lfG  = (unsigned short*)(ws + 58982400ull);
    unsigned short* a1h  = (unsigned short*)(ws + 117964800ull);
    float* Gpart = (float*)(ws + 117964800ull);   // aliases a1h (dead first)
    float* sq    = (float*)(ws + 228556800ull);
    int*   idx   = (int*)  (ws + 228602880ull);
    unsigned short* w2h = (unsigned short*)(ws + 206438400ull);
    unsigned short* w1h = (unsigned short*)(ws + 206438400ull + 147456ull);

    hipLaunchKernelGGL(k0g_pack, dim3(2400), dim3(256), 0, stream, lf_fea, lfG, lfVh);
    hipLaunchKernelGGL(k1_sq,    dim3(360),  dim3(256), 0, stream, lf_fea, sq);
    hipLaunchKernelGGL(k2a_gram, dim3(1440), dim3(256), 0, stream, lf_fea, Gpart);
    hipLaunchKernelGGL(k3_topk,  dim3(2880), dim3(256), 0, stream, Gpart, sq, idx);
    hipLaunchKernelGGL(kw1_conv, dim3(96),   dim3(256), 0, stream, w1, w1h);
    hipLaunchKernelGGL(kw2_conv, dim3(288),  dim3(256), 0, stream, w2, w2h);
    hipLaunchKernelGGL(k4_conv1, dim3(5760), dim3(256), 0, stream, lfG, w1h, idx, a1h);
    hipLaunchKernelGGL(k5n_conv3,dim3(1440), dim3(256), 0, stream, lfVh, a1h, w2h, outp);
}

// Round 28
// 822.983 us; speedup vs baseline: 1.1307x; 1.0002x over previous
//
#include <hip/hip_runtime.h>
#include <stdint.h>

// Fixed problem config
#define NN   2
#define ANU  5
#define CH   64
#define HH   96
#define WW   96
#define KK   6
#define PSHh 8
#define PNHh 12
#define BB   (NN*PNHh)        // 24
#define PP   (ANU*WW)         // 480
#define CCD  (CH*ANU*PSHh)    // 2560
#define IMG_HW (HH*WW)            // 9216
#define IMG_STRIDE (CH*HH*WW)     // 589824 floats per input image
#define LFV_IMG (CH*ANU*HH)       // 30720 elems per (n,v,w) image in lfVh / a1h

typedef int   i32x4 __attribute__((ext_vector_type(4)));
typedef float f32x4 __attribute__((ext_vector_type(4)));

__device__ __forceinline__ unsigned short f2bf(float f) {
    unsigned int u = __float_as_uint(f);
    return (unsigned short)((u + 0x7FFFu + ((u >> 16) & 1u)) >> 16);
}

__device__ __forceinline__ void mfma_bf16_16x16x32(f32x4& d, i32x4 a, i32x4 b) {
    asm volatile("v_mfma_f32_16x16x32_bf16 %0, %1, %2, %0"
                 : "+v"(d) : "v"(a), "v"(b));
}

// ---------------------------------------------------------------------------
// K0g: pack lf_fea -> lfG (gather-optimal) AND lfVh, one input read
//      (r27 verbatim, passing)
// ---------------------------------------------------------------------------
__global__ __launch_bounds__(256) void k0g_pack(const float* __restrict__ lf,
                                                unsigned short* __restrict__ lfG,
                                                unsigned short* __restrict__ lfVh) {
    int blk = blockIdx.x;            // ((img*12 + pnh)*4 + ct), grid 2400
    int ct = blk & 3; int r = blk >> 2;
    int pnh = r % 12, img = r / 12;
    int n = img / 25, rr = img % 25, u = rr / 5, v = rr % 5;
    int c0 = ct * 16;
    __shared__ float tile[16][8][97];
    int t = threadIdx.x;
    const float* src = lf + (size_t)img * IMG_STRIDE + (size_t)c0 * IMG_HW + pnh*768;
#pragma unroll
    for (int i = 0; i < 12; ++i) {
        int e = i*256 + t;           // 3072 float4
        int ci = e / 192, r2 = e % 192, psh = r2 / 24, q2 = r2 % 24;
        float4 vv = *(const float4*)(src + (size_t)ci*IMG_HW + psh*96 + q2*4);
        tile[ci][psh][q2*4+0]=vv.x; tile[ci][psh][q2*4+1]=vv.y;
        tile[ci][psh][q2*4+2]=vv.z; tile[ci][psh][q2*4+3]=vv.w;
    }
    __syncthreads();
    size_t ob = ((size_t)((n*12+pnh)*480 + v*96)) * 2560 + c0*40 + u*8;
#pragma unroll
    for (int i = 0; i < 24; ++i) {
        int e = i*256 + t;           // 6144 units = (w, ci, psh-pair)
        int w = e >> 6, r2 = e & 63, ci = r2 >> 2, pp = r2 & 3;
        size_t off = ob + (size_t)w*2560 + ci*40 + pp*2;
        lfG[off]     = f2bf(tile[ci][pp*2][w]);
        lfG[off + 1] = f2bf(tile[ci][pp*2+1][w]);
    }
    size_t vb = (size_t)((n*5 + v)*96) * LFV_IMG + (size_t)c0*480 + u*96 + pnh*8;
#pragma unroll
    for (int i = 0; i < 48; ++i) {
        int e = i*256 + t;           // 12288 u16 stores = (w, ci, psh)
        int psh = e & 7, r3 = e >> 3;
        int ci = r3 & 15, w = r3 >> 4;
        lfVh[vb + (size_t)w*LFV_IMG + ci*480 + psh] = f2bf(tile[ci][psh][w]);
    }
}

// ---------------------------------------------------------------------------
// K1: sq[b][p] (fp64 accumulate), 8-way column split per row; 360 blocks
// ---------------------------------------------------------------------------
__global__ __launch_bounds__(256) void k1_sq(const float* __restrict__ lf_fea,
                                             float* __restrict__ sq) {
    int t = threadIdx.x;
    int row = blockIdx.x * 32 + (t & 31);      // 0..11519
    int cp = t >> 5;                           // 0..7
    int b = row / PP, p = row % PP;
    int n = b / PNHh, pnh = b % PNHh;
    int v = p / WW, w = p % WW;
    double acc = 0.0;
    for (int ci = 0; ci < 8; ++ci) {
        int c = cp * 8 + ci;
        for (int u = 0; u < 5; ++u) {
            const float* s = lf_fea + ((size_t)((n*25 + u*5 + v)*64 + c)) * IMG_HW
                           + pnh*8*96 + w;
#pragma unroll
            for (int psh = 0; psh < 8; ++psh) {
                float x = s[psh*96];
                acc += (double)x * (double)x;
            }
        }
    }
    __shared__ double red[256];
    red[t] = acc;
    __syncthreads();
    if (t < 32) {
        double ss = 0.0;
#pragma unroll
        for (int j = 0; j < 8; ++j) ss += red[j * 32 + t];
        sq[blockIdx.x * 32 + t] = (float)ss;
    }
}

// ---------------------------------------------------------------------------
// K2a: partial Gram, symmetric (vr<=vc), K-split 4; grid 1440  (r27 verbatim)
// ---------------------------------------------------------------------------
__global__ __launch_bounds__(256) void k2a_gram(const float* __restrict__ lf_fea,
                                                float* __restrict__ Gpart) {
    const int VRt[15] = {0,0,0,0,0,1,1,1,1,2,2,2,3,3,4};
    const int VCt[15] = {0,1,2,3,4,1,2,3,4,2,3,4,3,4,4};
    int blk = blockIdx.x;            // b*60 + pr*4 + ks
    int b  = blk / 60;
    int r0 = blk % 60;
    int pr = r0 / 4, ks = r0 % 4;
    int vr = VRt[pr], vc = VCt[pr];
    int n = b / PNHh, pnh = b % PNHh;

    __shared__ float As[32][96];
    __shared__ float Bs[32][96];

    int t  = threadIdx.x;
    int tx = t & 31, ty = t >> 5;    // 32 x 8 compute tiling
    int sr = t >> 3, sw = t & 7;     // staging: row 0..31, col-base 0..7
    int m  = sr & 3;
    int wr0 = sw + 8 * m;
    int wr1 = sw + 8 * ((m + 1) & 3);
    int wr2 = sw + 8 * ((m + 2) & 3);
    int wr3 = sw + 8 * ((m + 3) & 3);
    float acc[12][3] = {};

    int kbase = ks * 640;
    for (int kc0 = kbase; kc0 < kbase + 640; kc0 += 32) {
        {
            int cc = kc0 + sr;
            int c = cc / 40, r2 = cc % 40, u = r2 >> 3, psh = r2 & 7;
            size_t off = ((size_t)((n*25 + u*5)*64 + c)) * IMG_HW + (pnh*8 + psh)*96;
            const float* pa = lf_fea + off + (size_t)vr * IMG_STRIDE;
            const float* pb = lf_fea + off + (size_t)vc * IMG_STRIDE;
#pragma unroll
            for (int g = 0; g < 3; ++g) {
                int w0 = wr0 + 32*g, w1 = wr1 + 32*g;
                int w2 = wr2 + 32*g, w3 = wr3 + 32*g;
                As[sr][w0] = pa[w0];  Bs[sr][w0] = pb[w0];
                As[sr][w1] = pa[w1];  Bs[sr][w1] = pb[w1];
                As[sr][w2] = pa[w2];  Bs[sr][w2] = pb[w2];
                As[sr][w3] = pa[w3];  Bs[sr][w3] = pb[w3];
            }
        }
        __syncthreads();
        float accC[12][3] = {};
#pragma unroll
        for (int kc = 0; kc < 32; ++kc) {
            float a[12], bq[3];
            *(float4*)&a[0] = *(const float4*)&As[kc][ty*12 + 0];
            *(float4*)&a[4] = *(const float4*)&As[kc][ty*12 + 4];
            *(float4*)&a[8] = *(const float4*)&As[kc][ty*12 + 8];
#pragma unroll
            for (int j = 0; j < 3; ++j) bq[j] = Bs[kc][tx*3 + j];
#pragma unroll
            for (int i = 0; i < 12; ++i)
#pragma unroll
                for (int j = 0; j < 3; ++j)
                    accC[i][j] = fmaf(a[i], bq[j], accC[i][j]);
        }
#pragma unroll
        for (int i = 0; i < 12; ++i)
#pragma unroll
            for (int j = 0; j < 3; ++j)
                acc[i][j] += accC[i][j];
        __syncthreads();
    }

    size_t gbase = ((size_t)(ks*600 + b*25 + vr*5 + vc)) * 9216;
#pragma unroll
    for (int i = 0; i < 12; ++i)
#pragma unroll
        for (int j = 0; j < 3; ++j)
            Gpart[gbase + (ty*12 + i)*96 + tx*3 + j] = acc[i][j];

    if (vr != vc) {
        size_t gbt = ((size_t)(ks*600 + b*25 + vc*5 + vr)) * 9216;
#pragma unroll
        for (int i = 0; i < 12; ++i)
#pragma unroll
            for (int j = 0; j < 3; ++j)
                Gpart[gbt + (tx*3 + j)*96 + ty*12 + i] = acc[i][j];
    }
}

// ---------------------------------------------------------------------------
// K3f: per-row top-6, dist computed inline from Gpart + sq  (r27 verbatim)
// ---------------------------------------------------------------------------
__global__ __launch_bounds__(256) void k3_topk(const float* __restrict__ Gpart,
                                               const float* __restrict__ sq,
                                               int* __restrict__ idx) {
    int wid  = (blockIdx.x * 256 + threadIdx.x) >> 6;  // global wave id
    int lane = threadIdx.x & 63;
    int b = wid / PP, p = wid % PP;
    int vr = p / 96, pl = p % 96;
    const float* gb = Gpart + ((size_t)(b*25 + vr*5)) * 9216 + pl*96;
    float sqp = sq[b*480 + p];

    unsigned long long key[8];
#pragma unroll
    for (int j = 0; j < 8; ++j) {
        int q = j*64 + lane;
        if (q < PP) {
            int vc = q / 96, ql = q % 96;
            size_t off = (size_t)vc * 9216 + ql;
            float g0 = gb[off];
            float g1 = gb[off +  600ull*9216];
            float g2 = gb[off + 1200ull*9216];
            float g3 = gb[off + 1800ull*9216];
            float gx = g0 + g1 + g2 + g3;
            float d  = sqp + sq[b*480 + q] - 2.0f * gx;
            unsigned int f = __float_as_uint(d);
            unsigned int mono = f ^ ((f & 0x80000000u) ? 0xFFFFFFFFu : 0x80000000u);
            key[j] = ((unsigned long long)mono << 32) | (unsigned int)q;
        } else {
            key[j] = ~0ull;
        }
    }
    int* outp = idx + ((size_t)b*PP + p) * KK;
    for (int k = 0; k < KK; ++k) {
        unsigned long long m = key[0];
#pragma unroll
        for (int j = 1; j < 8; ++j) m = (key[j] < m) ? key[j] : m;
        for (int s = 1; s < 64; s <<= 1) {
            unsigned long long o = __shfl_xor(m, s, 64);
            m = (o < m) ? o : m;
        }
        if (lane == 0) outp[k] = (int)(m & 0xFFFFFFFFu);
#pragma unroll
        for (int j = 0; j < 8; ++j) if (key[j] == m) key[j] = ~0ull;
    }
}

// ---------------------------------------------------------------------------
// kw1: w1 -> bf16 flat copy w1h[co][k*64+c]  (passing, verbatim)
// ---------------------------------------------------------------------------
__global__ __launch_bounds__(256) void kw1_conv(const float* __restrict__ w1,
                                                unsigned short* __restrict__ w1h) {
    int e = blockIdx.x * 256 + threadIdx.x;   // 24576 total, grid 96
    if (e < 24576) w1h[e] = f2bf(w1[e]);
}

// ---------------------------------------------------------------------------
// kw2: reorder w2 -> bf16 w2h[co][cc][tap][ci64] (passing, verbatim)
// ---------------------------------------------------------------------------
__global__ __launch_bounds__(256) void kw2_conv(const float* __restrict__ w2,
                                                unsigned short* __restrict__ w2h) {
    int e = blockIdx.x * 256 + threadIdx.x;   // 73728 total
    if (e < 73728) {
        int co = e / 1152, r = e % 1152;
        int cc = r / 576, r2 = r % 576;
        int tap = r2 / 64, ci_l = r2 % 64;
        w2h[e] = f2bf(w2[co*1152 + (cc*64 + ci_l)*9 + tap]);
    }
}

// ---------------------------------------------------------------------------
// K4: gather + 1x1 conv via inline-asm MFMA  (r27 verbatim, passing)
// ---------------------------------------------------------------------------
__global__ __launch_bounds__(256) void k4_conv1(const unsigned short* __restrict__ lfG,
                                                const unsigned short* __restrict__ w1h,
                                                const int* __restrict__ idxg,
                                                unsigned short* __restrict__ a1h) {
    int blk = blockIdx.x;            // b*240 + ptile
    int b = blk / 240, ptile = blk % 240;
    int n = b / PNHh, pnh = b % PNHh;
    int p0 = ptile * 2;

    __shared__ unsigned short Bs[80][384];   // [col][swizzled krow] bf16
    __shared__ int idxs[12];

    int t = threadIdx.x;
    if (t < 12) idxs[t] = idxg[(b*PP + p0 + t/6)*KK + (t % 6)];
    __syncthreads();

    // stage: 3840 units of 16B; unit = (pl, k, m); m -> (c = m/5, u = m%5)
    for (int i = 0; i < 15; ++i) {
        int e = i * 256 + t;         // 3840 exactly
        int pl = e / 1920, r = e % 1920;
        int k = r / 320, m = r % 320;
        int c = m / 5, u = m % 5;
        int q = idxs[pl*6 + k];
        i32x4 vv = *(const i32x4*)(lfG + ((size_t)(b*480 + q))*2560 + m*8);
        int colbase = pl*40 + u*8;   // multiple of 8
        int krow = k*64 + c;
        int kc = krow >> 3, kl = krow & 7;
        int kbase = kc & ~7, klo = kc & 7;
#pragma unroll
        for (int j = 0; j < 4; ++j) {
            unsigned int d = (unsigned int)vv[j];
            int j0 = 2*j, j1 = 2*j + 1;
            Bs[colbase + j0][((kbase | (klo ^ j0)) << 3) | kl] =
                (unsigned short)(d & 0xFFFFu);
            Bs[colbase + j1][((kbase | (klo ^ j1)) << 3) | kl] =
                (unsigned short)(d >> 16);
        }
    }
    __syncthreads();

    int lane = t & 63, wv = t >> 6;
    int l15 = lane & 15, hi = lane >> 4;
    int co0 = wv * 16;
    f32x4 acc[5] = {};
#pragma unroll
    for (int f = 0; f < 5; ++f)
        asm volatile("s_nop 1" : "+v"(acc[f]));

    const unsigned short* ap = w1h + (size_t)(co0 + l15) * 384 + hi * 8;
    for (int ks = 0; ks < 12; ++ks) {
        i32x4 a = *(const i32x4*)(ap + ks * 32);
        asm volatile("s_nop 1" : "+v"(a));
#pragma unroll
        for (int f = 0; f < 5; ++f) {
            int col = f * 16 + l15;
            int ch = ks * 4 + hi;            // chunk 0..47
            int chs = (ch & ~7) | ((ch & 7) ^ (col & 7));
            i32x4 bv = *(const i32x4*)&Bs[col][chs << 3];
            mfma_bf16_16x16x32(acc[f], a, bv);
        }
    }
#pragma unroll
    for (int f = 0; f < 5; ++f)
        asm volatile("s_nop 7\ns_nop 7" : "+v"(acc[f]));

    // epilogue: leaky + bf16 u16 stores; D map: col=lane&15, row=hi*4+reg
#pragma unroll
    for (int f = 0; f < 5; ++f) {
        int col = f * 16 + l15;
        int pg = p0 + col / 40, rr = col % 40;
        int u = rr >> 3, psh = rr & 7;
        size_t base = (size_t)((n*5 + pg/96)*96 + (pg%96)) * LFV_IMG
                    + (size_t)u * 96 + pnh*8 + psh;
#pragma unroll
        for (int rg = 0; rg < 4; ++rg) {
            float x = acc[f][rg];
            x = x > 0.f ? x : 0.1f * x;
            a1h[base + (size_t)(co0 + hi*4 + rg) * 480] = f2bf(x);
        }
    }
}

// ---------------------------------------------------------------------------
// K5n: 3x3 conv via inline-asm MFMA, u-fused tile (r27 core).
//      Staging index REMAP: e -> (g, clo, w, uin, cch) with clo = ci&7 now
//      wave-varying -> per write instruction lanes span ~16 banks (4-way)
//      instead of ~8 (8-16-way). Same unit set -> LDS contents bit-identical.
// ---------------------------------------------------------------------------
__global__ __launch_bounds__(256) void k5n_conv3(const unsigned short* __restrict__ lfVh,
                                                 const unsigned short* __restrict__ a1h,
                                                 const unsigned short* __restrict__ w2h,
                                                 float* __restrict__ outp) {
    int blk = blockIdx.x;             // grid 1440 = nv*144 + wt*6 + ht
    int ht = blk % 6;  int r = blk / 6;
    int wt = r % 24;   int nv = r / 24;    // nv = n*5 + v
    int w0 = wt * 4, h0 = ht * 16;
    int imgbase = nv * 96 + w0;

    __shared__ unsigned short ins[360][64];   // 46,080 B

    int t = threadIdx.x;
    int lane = t & 63, wv = t >> 6, l15 = lane & 15, hi = lane >> 4;
    int wl = l15 & 3;                 // output w within tile
    int hl = wv * 4 + (l15 >> 2);     // output h within tile (wave-split)

    f32x4 acc[5][4] = {};
#pragma unroll
    for (int u = 0; u < 5; ++u)
#pragma unroll
        for (int j = 0; j < 4; ++j)
            asm volatile("s_nop 1" : "+v"(acc[u][j]));

    for (int cc = 0; cc < 2; ++cc) {
        const unsigned short* basep = cc ? a1h : lfVh;
        if (cc) __syncthreads();
        // stage: e = (g, clo, w, uin, cch): 4 h-values, b16 scatter w/ guards
        for (int i = 0; i < 30; ++i) {
            int e = i * 256 + t;              // 7680 = 6*8*4*5*8
            int g   = e % 6;
            int clo = (e / 6) & 7;
            int w   = (e / 48) & 3;
            int uin = (e / 192) % 5;
            int cch = e / 960;                // 0..7
            int ci  = cch * 8 + clo;
            int hbase = h0 - 4 + g * 4;       // aligned chunk of 4 h-values
            unsigned short b0 = 0, b1 = 0, b2 = 0, b3 = 0;
            if (hbase >= 0 && hbase <= 92) {
                ushort4 vv = *(const ushort4*)(basep
                    + (size_t)(imgbase + w) * LFV_IMG
                    + (size_t)ci * 480 + uin * 96 + hbase);
                b0 = vv.x; b1 = vv.y; b2 = vv.z; b3 = vv.w;
            }
            int sbase = (w*5 + uin) * 18;
            int hp0 = g*4 - 3;                // hp of element 0 (in [-3, 17])
            if (hp0 >= 0) {                               // hp0 <= 17 always
                int s = sbase + hp0;
                ins[s][((cch ^ (s & 7)) << 3) | clo] = b0;
            }
            if (hp0 + 1 >= 0 && hp0 + 1 < 18) {
                int s = sbase + hp0 + 1;
                ins[s][((cch ^ (s & 7)) << 3) | clo] = b1;
            }
            if (hp0 + 2 >= 0 && hp0 + 2 < 18) {
                int s = sbase + hp0 + 2;
                ins[s][((cch ^ (s & 7)) << 3) | clo] = b2;
            }
            if (hp0 + 3 < 18) {                           // hp0+3 >= 0 always
                int s = sbase + hp0 + 3;
                ins[s][((cch ^ (s & 7)) << 3) | clo] = b3;
            }
        }
        __syncthreads();

        // compute: K-steps (du,dh,kk); B-frag per u feeds 4 co-frag MFMAs
        for (int du = 0; du < 3; ++du) {
#pragma unroll
            for (int dh = 0; dh < 3; ++dh)
#pragma unroll
            for (int kk = 0; kk < 2; ++kk) {
                const unsigned short* wp = w2h + cc*576 + (du*3 + dh)*64
                                         + kk*32 + hi*8 + (size_t)l15*1152;
                i32x4 a0 = *(const i32x4*)(wp);
                i32x4 a1f = *(const i32x4*)(wp + 16*1152);
                i32x4 a2 = *(const i32x4*)(wp + 32*1152);
                i32x4 a3 = *(const i32x4*)(wp + 48*1152);
#pragma unroll
                for (int u = 0; u < 5; ++u) {
                    int uin = u + du - 1;
                    if (uin < 0 || uin > 4) continue;   // u-halo: exact skip
                    int s = (wl*5 + uin)*18 + hl + dh;
                    i32x4 bv = *(const i32x4*)&ins[s][((kk*4 + hi) ^ (s & 7)) << 3];
                    mfma_bf16_16x16x32(acc[u][0], a0, bv);
                    mfma_bf16_16x16x32(acc[u][1], a1f, bv);
                    mfma_bf16_16x16x32(acc[u][2], a2, bv);
                    mfma_bf16_16x16x32(acc[u][3], a3, bv);
                }
            }
        }
        if (!cc) __syncthreads();   // protect ins reuse before second stage
    }
#pragma unroll
    for (int u = 0; u < 5; ++u)
#pragma unroll
        for (int j = 0; j < 4; ++j)
            asm volatile("s_nop 7\ns_nop 7" : "+v"(acc[u][j]));

    // leaky + permuted store: out[(n*25+u*5+v)][co][h0+hl][w0+wl]
    int n = nv / 5, v = nv % 5;
#pragma unroll
    for (int u = 0; u < 5; ++u) {
        size_t ob = (size_t)((n*25 + u*5 + v) * 64) * IMG_HW
                  + (size_t)(h0 + hl) * 96 + w0 + wl;
#pragma unroll
        for (int j = 0; j < 4; ++j) {
#pragma unroll
            for (int rg = 0; rg < 4; ++rg) {
                int co = j*16 + hi*4 + rg;
                float x = acc[u][j][rg];
                x = x > 0.f ? x : 0.1f * x;
                outp[ob + (size_t)co * IMG_HW] = x;
            }
        }
    }
}

// ---------------------------------------------------------------------------
extern "C" void kernel_launch(void* const* d_in, const int* in_sizes, int n_in,
                              void* d_out, int out_size, void* d_ws, size_t ws_size,
                              hipStream_t stream) {
    const float* lf_fea = (const float*)d_in[0];
    const float* w1     = (const float*)d_in[1];
    const float* w2     = (const float*)d_in[2];
    float* outp = (float*)d_out;

    char* ws = (char*)d_ws;
    // ws layout (bytes), end 228,672,000 (< proven 258 MB footprint):
    //   lfVh :  58,982,400 @ 0                       (bf16)
    //   lfG  :  58,982,400 @  58,982,400             (bf16, gather-optimal)
    //   a1h/Gpart union     @ 117,964,800, size 88,473,600
    //     (Gpart written k2a, read k3, dead before k4 writes a1h)
    //   w2h/w1h            @ 206,438,400
    //   sq   :      46,080 @ 228,556,800
    //   idx  :      69,120 @ 228,602,880   (end 228,672,000)
    unsigned short* lfVh = (unsigned short*)(ws);
    unsigned short* lfG  = (unsigned short*)(ws + 58982400ull);
    unsigned short* a1h  = (unsigned short*)(ws + 117964800ull);
    float* Gpart = (float*)(ws + 117964800ull);   // aliases a1h (dead first)
    float* sq    = (float*)(ws + 228556800ull);
    int*   idx   = (int*)  (ws + 228602880ull);
    unsigned short* w2h = (unsigned short*)(ws + 206438400ull);
    unsigned short* w1h = (unsigned short*)(ws + 206438400ull + 147456ull);

    hipLaunchKernelGGL(k0g_pack, dim3(2400), dim3(256), 0, stream, lf_fea, lfG, lfVh);
    hipLaunchKernelGGL(k1_sq,    dim3(360),  dim3(256), 0, stream, lf_fea, sq);
    hipLaunchKernelGGL(k2a_gram, dim3(1440), dim3(256), 0, stream, lf_fea, Gpart);
    hipLaunchKernelGGL(k3_topk,  dim3(2880), dim3(256), 0, stream, Gpart, sq, idx);
    hipLaunchKernelGGL(kw1_conv, dim3(96),   dim3(256), 0, stream, w1, w1h);
    hipLaunchKernelGGL(kw2_conv, dim3(288),  dim3(256), 0, stream, w2, w2h);
    hipLaunchKernelGGL(k4_conv1, dim3(5760), dim3(256), 0, stream, lfG, w1h, idx, a1h);
    hipLaunchKernelGGL(k5n_conv3,dim3(1440), dim3(256), 0, stream, lfVh, a1h, w2h, outp);
}